// Round 11
// baseline (386.616 us; speedup 1.0000x reference)
//
#include <hip/hip_runtime.h>
#include <hip/hip_bf16.h>
#include <math.h>

#define NN 20000
#define EE 320000
#define FXX 256
#define FWW 128
#define NH 4

typedef __attribute__((ext_vector_type(8))) short short8v;
typedef __attribute__((ext_vector_type(4))) float f32x4;

static __device__ __forceinline__ float bf2f(unsigned short s) {
    unsigned int u = ((unsigned int)s) << 16;
    return __builtin_bit_cast(float, u);
}

// round-to-nearest-even fp32 -> bf16 bits
static __device__ __forceinline__ unsigned short f2bf_u16(float f) {
    unsigned int u = __builtin_bit_cast(unsigned int, f);
    unsigned int r = 0x7fffu + ((u >> 16) & 1u);
    return (unsigned short)((u + r) >> 16);
}

// ---------------------------------------------------------------- cast x & dat to bf16
__global__ __launch_bounds__(256) void cast2_kernel(const float* __restrict__ a, __hip_bfloat16* __restrict__ ab, int na,
                                                    const float* __restrict__ b, __hip_bfloat16* __restrict__ bb, int nb)
{
    int i = (blockIdx.x * 256 + threadIdx.x) * 4;
    if (i < na) {
        float4 v = *(const float4*)(a + i);
        ab[i + 0] = __float2bfloat16(v.x); ab[i + 1] = __float2bfloat16(v.y);
        ab[i + 2] = __float2bfloat16(v.z); ab[i + 3] = __float2bfloat16(v.w);
    } else {
        int j = i - na;
        if (j < nb) {
            float4 v = *(const float4*)(b + j);
            bb[j + 0] = __float2bfloat16(v.x); bb[j + 1] = __float2bfloat16(v.y);
            bb[j + 2] = __float2bfloat16(v.z); bb[j + 3] = __float2bfloat16(v.w);
        }
    }
}

// ---------------------------------------------------------------- w~ = W_h @ a (score projection vectors), fp32
struct WscItem { const float* W; const float* as_; const float* ad_; int Fin; };
struct WscParams { WscItem t[4]; };

__global__ __launch_bounds__(256) void wsc_kernel(WscParams p, float* __restrict__ wsc)
{
    int L = blockIdx.z;
    WscItem it = p.t[L];
    int wid = threadIdx.x >> 6, lane = threadIdx.x & 63;
    int r = blockIdx.x * 4 + wid;
    if (r >= it.Fin * 4) return;
    int h = r / it.Fin, k = r - h * it.Fin;
    float2 w2 = *(const float2*)(it.W + ((size_t)(h * it.Fin + k)) * 128 + 2 * lane);
    float2 s2 = *(const float2*)(it.as_ + h * 128 + 2 * lane);
    float2 d2 = *(const float2*)(it.ad_ + h * 128 + 2 * lane);
    float vs = w2.x * s2.x + w2.y * s2.y;
    float vd = w2.x * d2.x + w2.y * d2.y;
    #pragma unroll
    for (int o = 32; o; o >>= 1) { vs += __shfl_xor(vs, o); vd += __shfl_xor(vd, o); }
    if (lane == 0) {
        wsc[(size_t)L * 2048 + h * 256 + k] = vs;
        wsc[(size_t)L * 2048 + (4 + h) * 256 + k] = vd;
    }
}

// ---------------------------------------------------------------- combined GEMM weights: [0.25*W_0;..;0.25*W_3;R] transposed -> [128][KK] bf16
struct WcItem { const float* W; const float* R; __hip_bfloat16* dst; int Fin; int KK; int total; };
struct WcParams { WcItem t[4]; };

__global__ __launch_bounds__(256) void wcomb_kernel(WcParams p)
{
    WcItem it = p.t[blockIdx.z];
    int idx = blockIdx.x * 256 + threadIdx.x;
    if (idx >= it.total) return;     // total = 128*KK
    int c = idx / it.KK;
    int k5 = idx - c * it.KK;
    int f4 = it.Fin * 4;
    float v;
    if (k5 < f4) {
        int h = k5 / it.Fin, k = k5 - h * it.Fin;
        v = 0.25f * it.W[((size_t)(h * it.Fin + k)) * 128 + c];
    } else {
        v = it.R[(size_t)(k5 - f4) * 128 + c];
    }
    it.dst[(size_t)c * it.KK + k5] = __float2bfloat16(v);
}

// ---------------------------------------------------------------- scores: s[n][j] = X[n] . w~[j], wave per node
template<int CF>
__global__ __launch_bounds__(256) void score_kernel(const __hip_bfloat16* __restrict__ Xb,
                                                    const float* __restrict__ wsc,   // [8][256]
                                                    float* __restrict__ ssrc,
                                                    float* __restrict__ sdst)
{
    const int Fin = CF * 64;
    int wid = threadIdx.x >> 6, lane = threadIdx.x & 63;
    int n = blockIdx.x * 4 + wid;
    if (n >= NN) return;
    int c0 = lane * CF;
    union { unsigned u[CF / 2]; unsigned short s[CF]; } ld;
    #pragma unroll
    for (int w = 0; w < CF / 2; ++w)
        ld.u[w] = *(const unsigned*)(Xb + (size_t)n * Fin + c0 + w * 2);
    float xv[CF];
    #pragma unroll
    for (int i = 0; i < CF; ++i) xv[i] = bf2f(ld.s[i]);
    float acc[8];
    #pragma unroll
    for (int j = 0; j < 8; ++j) {
        const float* w = wsc + j * 256 + c0;
        float s = 0.f;
        #pragma unroll
        for (int i = 0; i < CF; ++i) s += xv[i] * w[i];
        acc[j] = s;
    }
    #pragma unroll
    for (int o = 32; o; o >>= 1)
        #pragma unroll
        for (int j = 0; j < 8; ++j) acc[j] += __shfl_xor(acc[j], o);
    if (lane == 0) {
        *(float4*)(ssrc + (size_t)n * 4) = make_float4(acc[0], acc[1], acc[2], acc[3]);
        *(float4*)(sdst + (size_t)n * 4) = make_float4(acc[4], acc[5], acc[6], acc[7]);
    }
}

// ---------------------------------------------------------------- CSR build
__global__ __launch_bounds__(256) void hist_kernel(const int* __restrict__ src, int* __restrict__ cnt)
{
    int i = blockIdx.x * blockDim.x + threadIdx.x;
    if (i < EE) atomicAdd(&cnt[src[i]], 1);
}

__global__ __launch_bounds__(1024) void scan_kernel(const int* __restrict__ cnt, int* __restrict__ row_ptr)
{
    __shared__ int lds[1024];
    int t = threadIdx.x;
    const int CH = 20;
    int start = t * CH, end = start + CH; if (end > NN) end = NN;
    int sum = 0;
    if (start < NN) for (int i = start; i < end; ++i) sum += cnt[i];
    lds[t] = sum;
    __syncthreads();
    for (int o = 1; o < 1024; o <<= 1) {
        int v = (t >= o) ? lds[t - o] : 0;
        __syncthreads();
        lds[t] += v;
        __syncthreads();
    }
    int run = lds[t] - sum;
    if (start < NN) for (int i = start; i < end; ++i) { row_ptr[i] = run; run += cnt[i]; }
    if (t == 1023) row_ptr[NN] = lds[1023];
}

__global__ __launch_bounds__(256) void scatter_kernel(const int* __restrict__ src,
                                                      const int* __restrict__ dst,
                                                      const int* __restrict__ row_ptr,
                                                      int* __restrict__ off,
                                                      int* __restrict__ csr_dst)
{
    int i = blockIdx.x * blockDim.x + threadIdx.x;
    if (i >= EE) return;
    int s = src[i];
    int p = row_ptr[s] + atomicAdd(&off[s], 1);
    csr_dst[p] = dst[i];
}

// ---------------------------------------------------------------- FUSED softmax + aggregate -> Cat = [G0|G1|G2|G3|X]
// wave per node. Softmax: lane=edge (chunk 0 scalar regs). Aggregate: 4x16-lane
// groups, group g owns edges base+g (4 edges in flight); lane covers Fin/16 feats
// (16-32B vector loads). Cross-group combine via 2 shfl_xor rounds at the end.
template<int CF>
__global__ __launch_bounds__(256) void agg_cat_kernel(const __hip_bfloat16* __restrict__ Xb,   // [N][Fin]
                                                      const float* __restrict__ ssrc,
                                                      const float* __restrict__ sdst,
                                                      const int* __restrict__ row_ptr,
                                                      const int* __restrict__ csr_dst,
                                                      __hip_bfloat16* __restrict__ Cat)       // [N][5*Fin]
{
    const int Fin = CF * 64, KK = 5 * Fin;
    const int F16 = CF * 4;                 // features per lane in 16-lane mode
    int wid = threadIdx.x >> 6, lane = threadIdx.x & 63;
    int n = blockIdx.x * 4 + wid;
    if (n >= NN) return;
    int r0 = row_ptr[n], r1 = row_ptr[n + 1];
    int deg = r1 - r0;
    int g = lane >> 4, q = lane & 15;

    float acc[4][F16] = {};

    if (deg > 0) {
        float4 sn = *(const float4*)(ssrc + (size_t)n * 4);
        auto comp_e = [&](int s, int& dout) -> float4 {
            int d = csr_dst[r0 + s];
            dout = d;
            float4 sd = *(const float4*)(sdst + (size_t)d * 4);
            float4 e; float v;
            v = sn.x + sd.x; e.x = v >= 0.f ? v : 0.2f * v;
            v = sn.y + sd.y; e.y = v >= 0.f ? v : 0.2f * v;
            v = sn.z + sd.z; e.z = v >= 0.f ? v : 0.2f * v;
            v = sn.w + sd.w; e.w = v >= 0.f ? v : 0.2f * v;
            return e;
        };

        // ---- softmax over out-edges (chunk 0 in scalar regs, cold recompute beyond 64)
        float4 e0 = make_float4(-1e30f, -1e30f, -1e30f, -1e30f);
        int d0 = 0;
        if (lane < deg) e0 = comp_e(lane, d0);
        float4 m = e0;
        for (int s = lane + 64; s < deg; s += 64) {
            int dt; float4 ev = comp_e(s, dt);
            m.x = fmaxf(m.x, ev.x); m.y = fmaxf(m.y, ev.y);
            m.z = fmaxf(m.z, ev.z); m.w = fmaxf(m.w, ev.w);
        }
        #pragma unroll
        for (int o = 32; o; o >>= 1) {
            m.x = fmaxf(m.x, __shfl_xor(m.x, o));
            m.y = fmaxf(m.y, __shfl_xor(m.y, o));
            m.z = fmaxf(m.z, __shfl_xor(m.z, o));
            m.w = fmaxf(m.w, __shfl_xor(m.w, o));
        }
        float4 p0 = make_float4(0.f, 0.f, 0.f, 0.f);
        if (lane < deg) {
            p0.x = expf(e0.x - m.x); p0.y = expf(e0.y - m.y);
            p0.z = expf(e0.z - m.z); p0.w = expf(e0.w - m.w);
        }
        float4 den = p0;
        for (int s = lane + 64; s < deg; s += 64) {
            int dt; float4 ev = comp_e(s, dt);
            den.x += expf(ev.x - m.x); den.y += expf(ev.y - m.y);
            den.z += expf(ev.z - m.z); den.w += expf(ev.w - m.w);
        }
        #pragma unroll
        for (int o = 32; o; o >>= 1) {
            den.x += __shfl_xor(den.x, o); den.y += __shfl_xor(den.y, o);
            den.z += __shfl_xor(den.z, o); den.w += __shfl_xor(den.w, o);
        }
        den.x = 1.f / (den.x + 1e-16f); den.y = 1.f / (den.y + 1e-16f);
        den.z = 1.f / (den.z + 1e-16f); den.w = 1.f / (den.w + 1e-16f);

        float4 a0;
        a0.x = p0.x * den.x; a0.y = p0.y * den.y;
        a0.z = p0.z * den.z; a0.w = p0.w * den.w;

        // ---- aggregate: group g owns edges base+g
        for (int base = 0; base < deg; base += 4) {
            int j = base + g;
            bool valid = j < deg;
            int d = 0;
            float ax = 0.f, ay = 0.f, az = 0.f, aw = 0.f;
            if (j < 64) {
                d  = __shfl(d0, j);
                ax = __shfl(a0.x, j); ay = __shfl(a0.y, j);
                az = __shfl(a0.z, j); aw = __shfl(a0.w, j);
                if (!valid) { ax = ay = az = aw = 0.f; }
            } else if (valid) {          // cold: deg > 64
                d = csr_dst[r0 + j];
                float4 sd = *(const float4*)(sdst + (size_t)d * 4);
                float v; float4 e;
                v = sn.x + sd.x; e.x = v >= 0.f ? v : 0.2f * v;
                v = sn.y + sd.y; e.y = v >= 0.f ? v : 0.2f * v;
                v = sn.z + sd.z; e.z = v >= 0.f ? v : 0.2f * v;
                v = sn.w + sd.w; e.w = v >= 0.f ? v : 0.2f * v;
                ax = expf(e.x - m.x) * den.x; ay = expf(e.y - m.y) * den.y;
                az = expf(e.z - m.z) * den.z; aw = expf(e.w - m.w) * den.w;
            }
            if (valid) {
                union { short8v v8[F16 / 8]; unsigned short s[F16]; } ld;
                #pragma unroll
                for (int w = 0; w < F16 / 8; ++w)
                    ld.v8[w] = *(const short8v*)(Xb + (size_t)d * Fin + q * F16 + w * 8);
                float xv[F16];
                #pragma unroll
                for (int i = 0; i < F16; ++i) xv[i] = bf2f(ld.s[i]);
                #pragma unroll
                for (int i = 0; i < F16; ++i) {
                    acc[0][i] += ax * xv[i];
                    acc[1][i] += ay * xv[i];
                    acc[2][i] += az * xv[i];
                    acc[3][i] += aw * xv[i];
                }
            }
        }

        // ---- combine the 4 groups
        #pragma unroll
        for (int h = 0; h < 4; ++h)
            #pragma unroll
            for (int i = 0; i < F16; ++i) {
                acc[h][i] += __shfl_xor(acc[h][i], 16);
                acc[h][i] += __shfl_xor(acc[h][i], 32);
            }
    }

    __hip_bfloat16* crow = Cat + (size_t)n * KK;
    if (lane < 16) {
        #pragma unroll
        for (int h = 0; h < 4; ++h) {
            union { short8v v8[F16 / 8]; unsigned short s[F16]; } pk;
            #pragma unroll
            for (int i = 0; i < F16; ++i) pk.s[i] = f2bf_u16(acc[h][i]);
            #pragma unroll
            for (int w = 0; w < F16 / 8; ++w)
                *(short8v*)(crow + h * Fin + q * F16 + w * 8) = pk.v8[w];
        }
    }
    // X tail copy (all lanes, CF features each)
    #pragma unroll
    for (int w = 0; w < CF / 2; ++w)
        *(unsigned*)(crow + 4 * Fin + lane * CF + w * 2) =
            *(const unsigned*)(Xb + (size_t)n * Fin + lane * CF + w * 2);
}

// ---------------------------------------------------------------- MFMA GEMM + ELU + fused channel-sum (SE pooling)
// block = 32 rows x 128 cols, 4 waves each 16x64; reg-staged dbuf, 1 barrier/iter
template<int KK>
__global__ __launch_bounds__(256) void gemm_elu(const __hip_bfloat16* __restrict__ Cat,
                                                const __hip_bfloat16* __restrict__ Wct,   // [128][KK]
                                                float* __restrict__ xout,
                                                __hip_bfloat16* __restrict__ xbout,
                                                float* __restrict__ sums, int ch)
{
    const int BK = 64;
    const int NIT = KK / BK;
    __shared__ short As[2][32 * 72];    // [row][72] (+8 pad, rows 16B-aligned)
    __shared__ short Bs[2][128 * 72];   // [col][72]
    __shared__ float ls[4];

    int tid = threadIdx.x, lane = tid & 63, wid = tid >> 6;
    int wr = wid >> 1, wc = wid & 1;
    int ar = lane & 15, kg = lane >> 4;
    int row0 = blockIdx.x * 32;         // 20000 = 32*625, no tail

    int a_row = tid >> 3, a_seg = tid & 7;
    int b_col = tid >> 1, b_seg0 = (tid & 1) * 4;

    const __hip_bfloat16* Ag = Cat + (size_t)(row0 + a_row) * KK + a_seg * 8;
    const __hip_bfloat16* Bg = Wct + (size_t)b_col * KK + b_seg0 * 8;

    short8v fa, fb0, fb1, fb2, fb3;

    f32x4 acc[4] = {};

    fa  = *(const short8v*)(Ag);
    fb0 = *(const short8v*)(Bg);
    fb1 = *(const short8v*)(Bg + 8);
    fb2 = *(const short8v*)(Bg + 16);
    fb3 = *(const short8v*)(Bg + 24);
    *(short8v*)(&As[0][a_row * 72 + a_seg * 8]) = fa;
    *(short8v*)(&Bs[0][b_col * 72 + (b_seg0 + 0) * 8]) = fb0;
    *(short8v*)(&Bs[0][b_col * 72 + (b_seg0 + 1) * 8]) = fb1;
    *(short8v*)(&Bs[0][b_col * 72 + (b_seg0 + 2) * 8]) = fb2;
    *(short8v*)(&Bs[0][b_col * 72 + (b_seg0 + 3) * 8]) = fb3;

    int cur = 0;
    for (int it = 0; it < NIT; ++it) {
        if (it + 1 < NIT) {
            int kb = (it + 1) * BK;
            fa  = *(const short8v*)(Ag + kb);
            fb0 = *(const short8v*)(Bg + kb);
            fb1 = *(const short8v*)(Bg + kb + 8);
            fb2 = *(const short8v*)(Bg + kb + 16);
            fb3 = *(const short8v*)(Bg + kb + 24);
        }
        __syncthreads();
        #pragma unroll
        for (int ks = 0; ks < 2; ++ks) {
            short8v a = *(const short8v*)(&As[cur][(wr * 16 + ar) * 72 + ks * 32 + kg * 8]);
            #pragma unroll
            for (int nb = 0; nb < 4; ++nb) {
                short8v b = *(const short8v*)(&Bs[cur][(wc * 64 + nb * 16 + ar) * 72 + ks * 32 + kg * 8]);
                acc[nb] = __builtin_amdgcn_mfma_f32_16x16x32_bf16(a, b, acc[nb], 0, 0, 0);
            }
        }
        if (it + 1 < NIT) {
            int nb2 = cur ^ 1;
            *(short8v*)(&As[nb2][a_row * 72 + a_seg * 8]) = fa;
            *(short8v*)(&Bs[nb2][b_col * 72 + (b_seg0 + 0) * 8]) = fb0;
            *(short8v*)(&Bs[nb2][b_col * 72 + (b_seg0 + 1) * 8]) = fb1;
            *(short8v*)(&Bs[nb2][b_col * 72 + (b_seg0 + 2) * 8]) = fb2;
            *(short8v*)(&Bs[nb2][b_col * 72 + (b_seg0 + 3) * 8]) = fb3;
        }
        cur ^= 1;
    }

    float lsum = 0.f;
    int rsub = (lane >> 4) * 4;
    #pragma unroll
    for (int nb = 0; nb < 4; ++nb) {
        int col = wc * 64 + nb * 16 + ar;
        #pragma unroll
        for (int r = 0; r < 4; ++r) {
            int row = row0 + wr * 16 + rsub + r;
            float v = acc[nb][r];
            v = v > 0.f ? v : expm1f(v);
            lsum += v;
            xout[(size_t)row * 128 + col] = v;
            xbout[(size_t)row * 128 + col] = __float2bfloat16(v);
        }
    }
    // fused SE pooling: block-level sum -> one atomic
    #pragma unroll
    for (int o = 32; o; o >>= 1) lsum += __shfl_xor(lsum, o);
    if (lane == 0) ls[wid] = lsum;
    __syncthreads();
    if (tid == 0) atomicAdd(&sums[ch], ls[0] + ls[1] + ls[2] + ls[3]);
}

// ---------------------------------------------------------------- SE MLP -> att[4]
__global__ void att_kernel(const float* __restrict__ sums,
                           const float* __restrict__ fc1w, const float* __restrict__ fc1b,
                           const float* __restrict__ fc2w, const float* __restrict__ fc2b,
                           float* __restrict__ att)
{
    if (threadIdx.x != 0 || blockIdx.x != 0) return;
    float avg[4];
    for (int c = 0; c < 4; ++c) avg[c] = sums[c] * (1.f / (NN * 128.f));
    float z[20];
    for (int j = 0; j < 20; ++j) {
        float v = fc1b[j];
        for (int c = 0; c < 4; ++c) v += avg[c] * fc1w[c * 20 + j];
        z[j] = v;
    }
    for (int c = 0; c < 4; ++c) {
        float v = fc2b[c];
        for (int j = 0; j < 20; ++j) v += z[j] * fc2w[j * 4 + c];
        att[c] = 1.f / (1.f + expf(-v));
    }
}

__global__ __launch_bounds__(256) void final_kernel(const float* __restrict__ x1,
                                                    const float* __restrict__ x2,
                                                    const float* __restrict__ d1,
                                                    const float* __restrict__ d2,
                                                    const float* __restrict__ att,
                                                    const float* __restrict__ convw,
                                                    const float* __restrict__ convb,
                                                    float* __restrict__ out)
{
    int i = blockIdx.x * blockDim.x + threadIdx.x;
    if (i >= NN * 128) return;
    float a0 = att[0], a1 = att[1], a2 = att[2], a3 = att[3];
    float w0 = convw[0], w1 = convw[1], w2 = convw[2], w3 = convw[3];
    float v = convb[0];
    v += w0 * fmaxf(a0 * x1[i], 0.f);
    v += w1 * fmaxf(a1 * x2[i], 0.f);
    v += w2 * fmaxf(a2 * d1[i], 0.f);
    v += w3 * fmaxf(a3 * d2[i], 0.f);
    out[i] = v;
}

// ---------------------------------------------------------------- host
extern "C" void kernel_launch(void* const* d_in, const int* in_sizes, int n_in,
                              void* d_out, int out_size, void* d_ws, size_t ws_size,
                              hipStream_t stream)
{
    (void)in_sizes; (void)n_in; (void)out_size; (void)ws_size;
    const float* x    = (const float*)d_in[0];
    const float* dat  = (const float*)d_in[1];
    const float* W1   = (const float*)d_in[2];
    const float* a1s  = (const float*)d_in[3];
    const float* a1d  = (const float*)d_in[4];
    const float* R1   = (const float*)d_in[5];
    const float* W2   = (const float*)d_in[6];
    const float* a2s  = (const float*)d_in[7];
    const float* a2d  = (const float*)d_in[8];
    const float* R2   = (const float*)d_in[9];
    const float* Wd1  = (const float*)d_in[10];
    const float* ad1s = (const float*)d_in[11];
    const float* ad1d = (const float*)d_in[12];
    const float* Rd1  = (const float*)d_in[13];
    const float* Wd2  = (const float*)d_in[14];
    const float* ad2s = (const float*)d_in[15];
    const float* ad2d = (const float*)d_in[16];
    const float* Rd2  = (const float*)d_in[17];
    const float* fc1w = (const float*)d_in[18];
    const float* fc1b = (const float*)d_in[19];
    const float* fc2w = (const float*)d_in[20];
    const float* fc2b = (const float*)d_in[21];
    const float* convw= (const float*)d_in[22];
    const float* convb= (const float*)d_in[23];
    const int*   eidx = (const int*)d_in[24];
    const int* esrc = eidx;
    const int* edst = eidx + EE;
    float* out = (float*)d_out;

    char* base = (char*)d_ws;
    size_t woff = 0;
    auto alloc = [&](size_t bytes) -> void* {
        void* p = base + woff;
        woff = (woff + bytes + 255) & ~(size_t)255;
        return p;
    };
    __hip_bfloat16* Cat  = (__hip_bfloat16*)alloc((size_t)NN * 1280 * 2);
    float* X1    = (float*)alloc((size_t)NN * 128 * 4);
    float* X2    = (float*)alloc((size_t)NN * 128 * 4);
    float* D1    = (float*)alloc((size_t)NN * 128 * 4);
    float* D2    = (float*)alloc((size_t)NN * 128 * 4);
    __hip_bfloat16* XbX   = (__hip_bfloat16*)alloc((size_t)NN * FXX * 2);
    __hip_bfloat16* XbDat = (__hip_bfloat16*)alloc((size_t)NN * FWW * 2);
    __hip_bfloat16* Xb1   = (__hip_bfloat16*)alloc((size_t)NN * 128 * 2);
    __hip_bfloat16* XbD1  = (__hip_bfloat16*)alloc((size_t)NN * 128 * 2);
    __hip_bfloat16* XbTmp = (__hip_bfloat16*)alloc((size_t)NN * 128 * 2);
    float* Wsc   = (float*)alloc((size_t)4 * 2048 * 4);
    __hip_bfloat16* Wct0 = (__hip_bfloat16*)alloc((size_t)128 * 1280 * 2);
    __hip_bfloat16* Wct1 = (__hip_bfloat16*)alloc((size_t)128 * 640 * 2);
    __hip_bfloat16* Wct2 = (__hip_bfloat16*)alloc((size_t)128 * 640 * 2);
    __hip_bfloat16* Wct3 = (__hip_bfloat16*)alloc((size_t)128 * 640 * 2);
    float* Ssrc  = (float*)alloc((size_t)NN * 4 * 4);
    float* Sdst  = (float*)alloc((size_t)NN * 4 * 4);
    int* RowPtr  = (int*)alloc((size_t)(NN + 1) * 4);
    int* Cnt     = (int*)alloc((size_t)NN * 4);
    int* Off     = (int*)alloc((size_t)NN * 4);
    int* CsrDst  = (int*)alloc((size_t)EE * 4);
    float* Sums  = (float*)alloc(16);
    float* Att   = (float*)alloc(16);

    // setup: casts, score vectors, combined weights, CSR
    {
        int na = NN * FXX, nb = NN * FWW;
        cast2_kernel<<<(na + nb + 1023) / 1024, 256, 0, stream>>>(x, XbX, na, dat, XbDat, nb);
        WscParams WP;
        WP.t[0] = { W1,  a1s,  a1d,  FXX };
        WP.t[1] = { W2,  a2s,  a2d,  FWW };
        WP.t[2] = { Wd1, ad1s, ad1d, FWW };
        WP.t[3] = { Wd2, ad2s, ad2d, FWW };
        wsc_kernel<<<dim3(256, 1, 4), 256, 0, stream>>>(WP, Wsc);
        WcParams CP;
        CP.t[0] = { W1,  R1,  Wct0, FXX, 1280, 128 * 1280 };
        CP.t[1] = { W2,  R2,  Wct1, FWW, 640,  128 * 640 };
        CP.t[2] = { Wd1, Rd1, Wct2, FWW, 640,  128 * 640 };
        CP.t[3] = { Wd2, Rd2, Wct3, FWW, 640,  128 * 640 };
        wcomb_kernel<<<dim3(640, 1, 4), 256, 0, stream>>>(CP);
    }
    hipMemsetAsync(Cnt, 0, (size_t)NN * 4, stream);
    hipMemsetAsync(Off, 0, (size_t)NN * 4, stream);
    hipMemsetAsync(Sums, 0, 16, stream);
    hist_kernel<<<(EE + 255) / 256, 256, 0, stream>>>(esrc, Cnt);
    scan_kernel<<<1, 1024, 0, stream>>>(Cnt, RowPtr);
    scatter_kernel<<<(EE + 255) / 256, 256, 0, stream>>>(esrc, edst, RowPtr, Off, CsrDst);

    auto layer = [&](const __hip_bfloat16* Xb, int CF, int Lidx, int ch,
                     const __hip_bfloat16* WctL, float* xout, __hip_bfloat16* xbout) {
        const float* wscL = Wsc + (size_t)Lidx * 2048;
        if (CF == 4) {
            score_kernel<4><<<(NN + 3) / 4, 256, 0, stream>>>(Xb, wscL, Ssrc, Sdst);
            agg_cat_kernel<4><<<(NN + 3) / 4, 256, 0, stream>>>(Xb, Ssrc, Sdst, RowPtr, CsrDst, Cat);
            gemm_elu<1280><<<NN / 32, 256, 0, stream>>>(Cat, WctL, xout, xbout, Sums, ch);
        } else {
            score_kernel<2><<<(NN + 3) / 4, 256, 0, stream>>>(Xb, wscL, Ssrc, Sdst);
            agg_cat_kernel<2><<<(NN + 3) / 4, 256, 0, stream>>>(Xb, Ssrc, Sdst, RowPtr, CsrDst, Cat);
            gemm_elu<640><<<NN / 32, 256, 0, stream>>>(Cat, WctL, xout, xbout, Sums, ch);
        }
    };

    layer(XbX,   4, 0, 0, Wct0, X1, Xb1);
    layer(Xb1,   2, 1, 1, Wct1, X2, XbTmp);
    layer(XbDat, 2, 2, 2, Wct2, D1, XbD1);
    layer(XbD1,  2, 3, 3, Wct3, D2, XbTmp);

    att_kernel<<<1, 64, 0, stream>>>(Sums, fc1w, fc1b, fc2w, fc2b, Att);
    final_kernel<<<(NN * 128 + 255) / 256, 256, 0, stream>>>(X1, X2, D1, D2, Att, convw, convb, out);
}

// Round 12
// 364.794 us; speedup vs baseline: 1.0598x; 1.0598x over previous
//
#include <hip/hip_runtime.h>
#include <hip/hip_bf16.h>
#include <math.h>

#define NN 20000
#define EE 320000
#define FXX 256
#define FWW 128
#define NH 4

typedef __attribute__((ext_vector_type(8))) short short8v;
typedef __attribute__((ext_vector_type(4))) float f32x4;

static __device__ __forceinline__ float bf2f(unsigned short s) {
    unsigned int u = ((unsigned int)s) << 16;
    return __builtin_bit_cast(float, u);
}

// round-to-nearest-even fp32 -> bf16 bits
static __device__ __forceinline__ unsigned short f2bf_u16(float f) {
    unsigned int u = __builtin_bit_cast(unsigned int, f);
    unsigned int r = 0x7fffu + ((u >> 16) & 1u);
    return (unsigned short)((u + r) >> 16);
}

// ---------------------------------------------------------------- cast x & dat to bf16
__global__ __launch_bounds__(256) void cast2_kernel(const float* __restrict__ a, __hip_bfloat16* __restrict__ ab, int na,
                                                    const float* __restrict__ b, __hip_bfloat16* __restrict__ bb, int nb)
{
    int i = (blockIdx.x * 256 + threadIdx.x) * 4;
    if (i < na) {
        float4 v = *(const float4*)(a + i);
        ab[i + 0] = __float2bfloat16(v.x); ab[i + 1] = __float2bfloat16(v.y);
        ab[i + 2] = __float2bfloat16(v.z); ab[i + 3] = __float2bfloat16(v.w);
    } else {
        int j = i - na;
        if (j < nb) {
            float4 v = *(const float4*)(b + j);
            bb[j + 0] = __float2bfloat16(v.x); bb[j + 1] = __float2bfloat16(v.y);
            bb[j + 2] = __float2bfloat16(v.z); bb[j + 3] = __float2bfloat16(v.w);
        }
    }
}

// ---------------------------------------------------------------- w~ = W_h @ a (score projection vectors), fp32
struct WscItem { const float* W; const float* as_; const float* ad_; int Fin; };
struct WscParams { WscItem t[4]; };

__global__ __launch_bounds__(256) void wsc_kernel(WscParams p, float* __restrict__ wsc)
{
    int L = blockIdx.z;
    WscItem it = p.t[L];
    int wid = threadIdx.x >> 6, lane = threadIdx.x & 63;
    int r = blockIdx.x * 4 + wid;
    if (r >= it.Fin * 4) return;
    int h = r / it.Fin, k = r - h * it.Fin;
    float2 w2 = *(const float2*)(it.W + ((size_t)(h * it.Fin + k)) * 128 + 2 * lane);
    float2 s2 = *(const float2*)(it.as_ + h * 128 + 2 * lane);
    float2 d2 = *(const float2*)(it.ad_ + h * 128 + 2 * lane);
    float vs = w2.x * s2.x + w2.y * s2.y;
    float vd = w2.x * d2.x + w2.y * d2.y;
    #pragma unroll
    for (int o = 32; o; o >>= 1) { vs += __shfl_xor(vs, o); vd += __shfl_xor(vd, o); }
    if (lane == 0) {
        wsc[(size_t)L * 2048 + h * 256 + k] = vs;
        wsc[(size_t)L * 2048 + (4 + h) * 256 + k] = vd;
    }
}

// ---------------------------------------------------------------- combined GEMM weights: [0.25*W_0;..;0.25*W_3;R] transposed -> [128][KK] bf16
struct WcItem { const float* W; const float* R; __hip_bfloat16* dst; int Fin; int KK; int total; };
struct WcParams { WcItem t[4]; };

__global__ __launch_bounds__(256) void wcomb_kernel(WcParams p)
{
    WcItem it = p.t[blockIdx.z];
    int idx = blockIdx.x * 256 + threadIdx.x;
    if (idx >= it.total) return;     // total = 128*KK
    int c = idx / it.KK;
    int k5 = idx - c * it.KK;
    int f4 = it.Fin * 4;
    float v;
    if (k5 < f4) {
        int h = k5 / it.Fin, k = k5 - h * it.Fin;
        v = 0.25f * it.W[((size_t)(h * it.Fin + k)) * 128 + c];
    } else {
        v = it.R[(size_t)(k5 - f4) * 128 + c];
    }
    it.dst[(size_t)c * it.KK + k5] = __float2bfloat16(v);
}

// ---------------------------------------------------------------- scores: s[n][j] = X[n] . w~[j], wave per node
template<int CF>
__global__ __launch_bounds__(256) void score_kernel(const __hip_bfloat16* __restrict__ Xb,
                                                    const float* __restrict__ wsc,   // [8][256]
                                                    float* __restrict__ ssrc,
                                                    float* __restrict__ sdst)
{
    const int Fin = CF * 64;
    int wid = threadIdx.x >> 6, lane = threadIdx.x & 63;
    int n = blockIdx.x * 4 + wid;
    if (n >= NN) return;
    int c0 = lane * CF;
    union { unsigned u[CF / 2]; unsigned short s[CF]; } ld;
    #pragma unroll
    for (int w = 0; w < CF / 2; ++w)
        ld.u[w] = *(const unsigned*)(Xb + (size_t)n * Fin + c0 + w * 2);
    float xv[CF];
    #pragma unroll
    for (int i = 0; i < CF; ++i) xv[i] = bf2f(ld.s[i]);
    float acc[8];
    #pragma unroll
    for (int j = 0; j < 8; ++j) {
        const float* w = wsc + j * 256 + c0;
        float s = 0.f;
        #pragma unroll
        for (int i = 0; i < CF; ++i) s += xv[i] * w[i];
        acc[j] = s;
    }
    #pragma unroll
    for (int o = 32; o; o >>= 1)
        #pragma unroll
        for (int j = 0; j < 8; ++j) acc[j] += __shfl_xor(acc[j], o);
    if (lane == 0) {
        *(float4*)(ssrc + (size_t)n * 4) = make_float4(acc[0], acc[1], acc[2], acc[3]);
        *(float4*)(sdst + (size_t)n * 4) = make_float4(acc[4], acc[5], acc[6], acc[7]);
    }
}

// ---------------------------------------------------------------- CSR build
__global__ __launch_bounds__(256) void hist_kernel(const int* __restrict__ src, int* __restrict__ cnt)
{
    int i = blockIdx.x * blockDim.x + threadIdx.x;
    if (i < EE) atomicAdd(&cnt[src[i]], 1);
}

__global__ __launch_bounds__(1024) void scan_kernel(const int* __restrict__ cnt, int* __restrict__ row_ptr)
{
    __shared__ int lds[1024];
    int t = threadIdx.x;
    const int CH = 20;
    int start = t * CH, end = start + CH; if (end > NN) end = NN;
    int sum = 0;
    if (start < NN) for (int i = start; i < end; ++i) sum += cnt[i];
    lds[t] = sum;
    __syncthreads();
    for (int o = 1; o < 1024; o <<= 1) {
        int v = (t >= o) ? lds[t - o] : 0;
        __syncthreads();
        lds[t] += v;
        __syncthreads();
    }
    int run = lds[t] - sum;
    if (start < NN) for (int i = start; i < end; ++i) { row_ptr[i] = run; run += cnt[i]; }
    if (t == 1023) row_ptr[NN] = lds[1023];
}

__global__ __launch_bounds__(256) void scatter_kernel(const int* __restrict__ src,
                                                      const int* __restrict__ dst,
                                                      const int* __restrict__ row_ptr,
                                                      int* __restrict__ off,
                                                      int* __restrict__ csr_dst)
{
    int i = blockIdx.x * blockDim.x + threadIdx.x;
    if (i >= EE) return;
    int s = src[i];
    int p = row_ptr[s] + atomicAdd(&off[s], 1);
    csr_dst[p] = dst[i];
}

// ---------------------------------------------------------------- FUSED softmax + aggregate -> Cat = [G0|G1|G2|G3|X]
// wave per node; chunk 0 (s==lane) scalar regs; aggregate loop is 4-wide
// software-pipelined (4 independent X-row loads in flight, readlane broadcasts).
template<int CF>
__global__ __launch_bounds__(256) void agg_cat_kernel(const __hip_bfloat16* __restrict__ Xb,   // [N][Fin]
                                                      const float* __restrict__ ssrc,
                                                      const float* __restrict__ sdst,
                                                      const int* __restrict__ row_ptr,
                                                      const int* __restrict__ csr_dst,
                                                      __hip_bfloat16* __restrict__ Cat)       // [N][5*Fin]
{
    const int Fin = CF * 64, KK = 5 * Fin;
    int wid = threadIdx.x >> 6, lane = threadIdx.x & 63;
    int n = blockIdx.x * 4 + wid;
    if (n >= NN) return;
    int r0 = row_ptr[n], r1 = row_ptr[n + 1];
    int deg = r1 - r0;

    float acc[4][CF] = {};

    if (deg > 0) {
        float4 sn = *(const float4*)(ssrc + (size_t)n * 4);
        auto comp_e = [&](int s, int& dout) -> float4 {
            int d = csr_dst[r0 + s];
            dout = d;
            float4 sd = *(const float4*)(sdst + (size_t)d * 4);
            float4 e; float v;
            v = sn.x + sd.x; e.x = v >= 0.f ? v : 0.2f * v;
            v = sn.y + sd.y; e.y = v >= 0.f ? v : 0.2f * v;
            v = sn.z + sd.z; e.z = v >= 0.f ? v : 0.2f * v;
            v = sn.w + sd.w; e.w = v >= 0.f ? v : 0.2f * v;
            return e;
        };

        // ---- softmax over out-edges (chunk 0 scalar regs, cold recompute beyond 64)
        float4 e0 = make_float4(-1e30f, -1e30f, -1e30f, -1e30f);
        int d0 = 0;
        if (lane < deg) e0 = comp_e(lane, d0);
        float4 m = e0;
        for (int s = lane + 64; s < deg; s += 64) {
            int dt; float4 ev = comp_e(s, dt);
            m.x = fmaxf(m.x, ev.x); m.y = fmaxf(m.y, ev.y);
            m.z = fmaxf(m.z, ev.z); m.w = fmaxf(m.w, ev.w);
        }
        #pragma unroll
        for (int o = 32; o; o >>= 1) {
            m.x = fmaxf(m.x, __shfl_xor(m.x, o));
            m.y = fmaxf(m.y, __shfl_xor(m.y, o));
            m.z = fmaxf(m.z, __shfl_xor(m.z, o));
            m.w = fmaxf(m.w, __shfl_xor(m.w, o));
        }
        float4 p0 = make_float4(0.f, 0.f, 0.f, 0.f);
        if (lane < deg) {
            p0.x = expf(e0.x - m.x); p0.y = expf(e0.y - m.y);
            p0.z = expf(e0.z - m.z); p0.w = expf(e0.w - m.w);
        }
        float4 den = p0;
        for (int s = lane + 64; s < deg; s += 64) {
            int dt; float4 ev = comp_e(s, dt);
            den.x += expf(ev.x - m.x); den.y += expf(ev.y - m.y);
            den.z += expf(ev.z - m.z); den.w += expf(ev.w - m.w);
        }
        #pragma unroll
        for (int o = 32; o; o >>= 1) {
            den.x += __shfl_xor(den.x, o); den.y += __shfl_xor(den.y, o);
            den.z += __shfl_xor(den.z, o); den.w += __shfl_xor(den.w, o);
        }
        den.x = 1.f / (den.x + 1e-16f); den.y = 1.f / (den.y + 1e-16f);
        den.z = 1.f / (den.z + 1e-16f); den.w = 1.f / (den.w + 1e-16f);

        float4 a0;
        a0.x = p0.x * den.x; a0.y = p0.y * den.y;
        a0.z = p0.z * den.z; a0.w = p0.w * den.w;

        // ---- hot aggregate: 4-wide pipelined broadcast-gather (chunk 0)
        int cnt0 = min(deg, 64);
        int last = cnt0 - 1;
        for (int base = 0; base < cnt0; base += 4) {
            int j1 = min(base + 1, last), j2 = min(base + 2, last), j3 = min(base + 3, last);
            int dv0 = __shfl(d0, base), dv1 = __shfl(d0, j1);
            int dv2 = __shfl(d0, j2),   dv3 = __shfl(d0, j3);
            union U { unsigned u[CF / 2]; unsigned short s[CF]; };
            U l0, l1, l2, l3;
            #pragma unroll
            for (int w = 0; w < CF / 2; ++w)
                l0.u[w] = *(const unsigned*)(Xb + (size_t)dv0 * Fin + lane * CF + w * 2);
            #pragma unroll
            for (int w = 0; w < CF / 2; ++w)
                l1.u[w] = *(const unsigned*)(Xb + (size_t)dv1 * Fin + lane * CF + w * 2);
            #pragma unroll
            for (int w = 0; w < CF / 2; ++w)
                l2.u[w] = *(const unsigned*)(Xb + (size_t)dv2 * Fin + lane * CF + w * 2);
            #pragma unroll
            for (int w = 0; w < CF / 2; ++w)
                l3.u[w] = *(const unsigned*)(Xb + (size_t)dv3 * Fin + lane * CF + w * 2);

            {
                float ax = __shfl(a0.x, base), ay = __shfl(a0.y, base);
                float az = __shfl(a0.z, base), aw = __shfl(a0.w, base);
                #pragma unroll
                for (int i = 0; i < CF; ++i) {
                    float xv = bf2f(l0.s[i]);
                    acc[0][i] += ax * xv; acc[1][i] += ay * xv;
                    acc[2][i] += az * xv; acc[3][i] += aw * xv;
                }
            }
            if (base + 1 < cnt0) {
                float ax = __shfl(a0.x, j1), ay = __shfl(a0.y, j1);
                float az = __shfl(a0.z, j1), aw = __shfl(a0.w, j1);
                #pragma unroll
                for (int i = 0; i < CF; ++i) {
                    float xv = bf2f(l1.s[i]);
                    acc[0][i] += ax * xv; acc[1][i] += ay * xv;
                    acc[2][i] += az * xv; acc[3][i] += aw * xv;
                }
            }
            if (base + 2 < cnt0) {
                float ax = __shfl(a0.x, j2), ay = __shfl(a0.y, j2);
                float az = __shfl(a0.z, j2), aw = __shfl(a0.w, j2);
                #pragma unroll
                for (int i = 0; i < CF; ++i) {
                    float xv = bf2f(l2.s[i]);
                    acc[0][i] += ax * xv; acc[1][i] += ay * xv;
                    acc[2][i] += az * xv; acc[3][i] += aw * xv;
                }
            }
            if (base + 3 < cnt0) {
                float ax = __shfl(a0.x, j3), ay = __shfl(a0.y, j3);
                float az = __shfl(a0.z, j3), aw = __shfl(a0.w, j3);
                #pragma unroll
                for (int i = 0; i < CF; ++i) {
                    float xv = bf2f(l3.s[i]);
                    acc[0][i] += ax * xv; acc[1][i] += ay * xv;
                    acc[2][i] += az * xv; acc[3][i] += aw * xv;
                }
            }
        }

        // ---- cold chunks (deg > 64): recompute alpha then broadcast
        for (int r = r0 + 64; r < r1; r += 64) {
            int cnt = min(64, r1 - r);
            int d = 0;
            float4 a4 = make_float4(0.f, 0.f, 0.f, 0.f);
            if (r + lane < r1) {
                int dt;
                float4 ev = comp_e(r - r0 + lane, dt);
                d = dt;
                a4.x = expf(ev.x - m.x) * den.x; a4.y = expf(ev.y - m.y) * den.y;
                a4.z = expf(ev.z - m.z) * den.z; a4.w = expf(ev.w - m.w) * den.w;
            }
            for (int j = 0; j < cnt; ++j) {
                int ddv = __shfl(d, j);
                float ax = __shfl(a4.x, j), ay = __shfl(a4.y, j);
                float az = __shfl(a4.z, j), aw = __shfl(a4.w, j);
                union { unsigned u[CF / 2]; unsigned short s[CF]; } ld;
                #pragma unroll
                for (int w = 0; w < CF / 2; ++w)
                    ld.u[w] = *(const unsigned*)(Xb + (size_t)ddv * Fin + lane * CF + w * 2);
                #pragma unroll
                for (int i = 0; i < CF; ++i) {
                    float xv = bf2f(ld.s[i]);
                    acc[0][i] += ax * xv; acc[1][i] += ay * xv;
                    acc[2][i] += az * xv; acc[3][i] += aw * xv;
                }
            }
        }
    }

    __hip_bfloat16* crow = Cat + (size_t)n * KK;
    #pragma unroll
    for (int h = 0; h < 4; ++h) {
        union { unsigned u[CF / 2]; unsigned short s[CF]; } pk;
        #pragma unroll
        for (int i = 0; i < CF; ++i) pk.s[i] = f2bf_u16(acc[h][i]);
        #pragma unroll
        for (int w = 0; w < CF / 2; ++w)
            *(unsigned*)(crow + h * Fin + lane * CF + w * 2) = pk.u[w];
    }
    // X tail copy
    #pragma unroll
    for (int w = 0; w < CF / 2; ++w)
        *(unsigned*)(crow + 4 * Fin + lane * CF + w * 2) =
            *(const unsigned*)(Xb + (size_t)n * Fin + lane * CF + w * 2);
}

// ---------------------------------------------------------------- MFMA GEMM + ELU + fused channel-sum (SE pooling)
// block = 32 rows x 128 cols, 4 waves each 16x64; reg-staged dbuf, 1 barrier/iter
template<int KK>
__global__ __launch_bounds__(256) void gemm_elu(const __hip_bfloat16* __restrict__ Cat,
                                                const __hip_bfloat16* __restrict__ Wct,   // [128][KK]
                                                float* __restrict__ xout,
                                                __hip_bfloat16* __restrict__ xbout,
                                                float* __restrict__ sums, int ch)
{
    const int BK = 64;
    const int NIT = KK / BK;
    __shared__ short As[2][32 * 72];    // [row][72] (+8 pad, rows 16B-aligned)
    __shared__ short Bs[2][128 * 72];   // [col][72]
    __shared__ float ls[4];

    int tid = threadIdx.x, lane = tid & 63, wid = tid >> 6;
    int wr = wid >> 1, wc = wid & 1;
    int ar = lane & 15, kg = lane >> 4;
    int row0 = blockIdx.x * 32;         // 20000 = 32*625, no tail

    int a_row = tid >> 3, a_seg = tid & 7;
    int b_col = tid >> 1, b_seg0 = (tid & 1) * 4;

    const __hip_bfloat16* Ag = Cat + (size_t)(row0 + a_row) * KK + a_seg * 8;
    const __hip_bfloat16* Bg = Wct + (size_t)b_col * KK + b_seg0 * 8;

    short8v fa, fb0, fb1, fb2, fb3;

    f32x4 acc[4] = {};

    fa  = *(const short8v*)(Ag);
    fb0 = *(const short8v*)(Bg);
    fb1 = *(const short8v*)(Bg + 8);
    fb2 = *(const short8v*)(Bg + 16);
    fb3 = *(const short8v*)(Bg + 24);
    *(short8v*)(&As[0][a_row * 72 + a_seg * 8]) = fa;
    *(short8v*)(&Bs[0][b_col * 72 + (b_seg0 + 0) * 8]) = fb0;
    *(short8v*)(&Bs[0][b_col * 72 + (b_seg0 + 1) * 8]) = fb1;
    *(short8v*)(&Bs[0][b_col * 72 + (b_seg0 + 2) * 8]) = fb2;
    *(short8v*)(&Bs[0][b_col * 72 + (b_seg0 + 3) * 8]) = fb3;

    int cur = 0;
    for (int it = 0; it < NIT; ++it) {
        if (it + 1 < NIT) {
            int kb = (it + 1) * BK;
            fa  = *(const short8v*)(Ag + kb);
            fb0 = *(const short8v*)(Bg + kb);
            fb1 = *(const short8v*)(Bg + kb + 8);
            fb2 = *(const short8v*)(Bg + kb + 16);
            fb3 = *(const short8v*)(Bg + kb + 24);
        }
        __syncthreads();
        #pragma unroll
        for (int ks = 0; ks < 2; ++ks) {
            short8v a = *(const short8v*)(&As[cur][(wr * 16 + ar) * 72 + ks * 32 + kg * 8]);
            #pragma unroll
            for (int nb = 0; nb < 4; ++nb) {
                short8v b = *(const short8v*)(&Bs[cur][(wc * 64 + nb * 16 + ar) * 72 + ks * 32 + kg * 8]);
                acc[nb] = __builtin_amdgcn_mfma_f32_16x16x32_bf16(a, b, acc[nb], 0, 0, 0);
            }
        }
        if (it + 1 < NIT) {
            int nb2 = cur ^ 1;
            *(short8v*)(&As[nb2][a_row * 72 + a_seg * 8]) = fa;
            *(short8v*)(&Bs[nb2][b_col * 72 + (b_seg0 + 0) * 8]) = fb0;
            *(short8v*)(&Bs[nb2][b_col * 72 + (b_seg0 + 1) * 8]) = fb1;
            *(short8v*)(&Bs[nb2][b_col * 72 + (b_seg0 + 2) * 8]) = fb2;
            *(short8v*)(&Bs[nb2][b_col * 72 + (b_seg0 + 3) * 8]) = fb3;
        }
        cur ^= 1;
    }

    float lsum = 0.f;
    int rsub = (lane >> 4) * 4;
    #pragma unroll
    for (int nb = 0; nb < 4; ++nb) {
        int col = wc * 64 + nb * 16 + ar;
        #pragma unroll
        for (int r = 0; r < 4; ++r) {
            int row = row0 + wr * 16 + rsub + r;
            float v = acc[nb][r];
            v = v > 0.f ? v : expm1f(v);
            lsum += v;
            xout[(size_t)row * 128 + col] = v;
            xbout[(size_t)row * 128 + col] = __float2bfloat16(v);
        }
    }
    // fused SE pooling: block-level sum -> one atomic
    #pragma unroll
    for (int o = 32; o; o >>= 1) lsum += __shfl_xor(lsum, o);
    if (lane == 0) ls[wid] = lsum;
    __syncthreads();
    if (tid == 0) atomicAdd(&sums[ch], ls[0] + ls[1] + ls[2] + ls[3]);
}

// ---------------------------------------------------------------- SE MLP -> att[4]
__global__ void att_kernel(const float* __restrict__ sums,
                           const float* __restrict__ fc1w, const float* __restrict__ fc1b,
                           const float* __restrict__ fc2w, const float* __restrict__ fc2b,
                           float* __restrict__ att)
{
    if (threadIdx.x != 0 || blockIdx.x != 0) return;
    float avg[4];
    for (int c = 0; c < 4; ++c) avg[c] = sums[c] * (1.f / (NN * 128.f));
    float z[20];
    for (int j = 0; j < 20; ++j) {
        float v = fc1b[j];
        for (int c = 0; c < 4; ++c) v += avg[c] * fc1w[c * 20 + j];
        z[j] = v;
    }
    for (int c = 0; c < 4; ++c) {
        float v = fc2b[c];
        for (int j = 0; j < 20; ++j) v += z[j] * fc2w[j * 4 + c];
        att[c] = 1.f / (1.f + expf(-v));
    }
}

__global__ __launch_bounds__(256) void final_kernel(const float* __restrict__ x1,
                                                    const float* __restrict__ x2,
                                                    const float* __restrict__ d1,
                                                    const float* __restrict__ d2,
                                                    const float* __restrict__ att,
                                                    const float* __restrict__ convw,
                                                    const float* __restrict__ convb,
                                                    float* __restrict__ out)
{
    int i = blockIdx.x * blockDim.x + threadIdx.x;
    if (i >= NN * 128) return;
    float a0 = att[0], a1 = att[1], a2 = att[2], a3 = att[3];
    float w0 = convw[0], w1 = convw[1], w2 = convw[2], w3 = convw[3];
    float v = convb[0];
    v += w0 * fmaxf(a0 * x1[i], 0.f);
    v += w1 * fmaxf(a1 * x2[i], 0.f);
    v += w2 * fmaxf(a2 * d1[i], 0.f);
    v += w3 * fmaxf(a3 * d2[i], 0.f);
    out[i] = v;
}

// ---------------------------------------------------------------- host
extern "C" void kernel_launch(void* const* d_in, const int* in_sizes, int n_in,
                              void* d_out, int out_size, void* d_ws, size_t ws_size,
                              hipStream_t stream)
{
    (void)in_sizes; (void)n_in; (void)out_size; (void)ws_size;
    const float* x    = (const float*)d_in[0];
    const float* dat  = (const float*)d_in[1];
    const float* W1   = (const float*)d_in[2];
    const float* a1s  = (const float*)d_in[3];
    const float* a1d  = (const float*)d_in[4];
    const float* R1   = (const float*)d_in[5];
    const float* W2   = (const float*)d_in[6];
    const float* a2s  = (const float*)d_in[7];
    const float* a2d  = (const float*)d_in[8];
    const float* R2   = (const float*)d_in[9];
    const float* Wd1  = (const float*)d_in[10];
    const float* ad1s = (const float*)d_in[11];
    const float* ad1d = (const float*)d_in[12];
    const float* Rd1  = (const float*)d_in[13];
    const float* Wd2  = (const float*)d_in[14];
    const float* ad2s = (const float*)d_in[15];
    const float* ad2d = (const float*)d_in[16];
    const float* Rd2  = (const float*)d_in[17];
    const float* fc1w = (const float*)d_in[18];
    const float* fc1b = (const float*)d_in[19];
    const float* fc2w = (const float*)d_in[20];
    const float* fc2b = (const float*)d_in[21];
    const float* convw= (const float*)d_in[22];
    const float* convb= (const float*)d_in[23];
    const int*   eidx = (const int*)d_in[24];
    const int* esrc = eidx;
    const int* edst = eidx + EE;
    float* out = (float*)d_out;

    char* base = (char*)d_ws;
    size_t woff = 0;
    auto alloc = [&](size_t bytes) -> void* {
        void* p = base + woff;
        woff = (woff + bytes + 255) & ~(size_t)255;
        return p;
    };
    __hip_bfloat16* Cat  = (__hip_bfloat16*)alloc((size_t)NN * 1280 * 2);
    float* X1    = (float*)alloc((size_t)NN * 128 * 4);
    float* X2    = (float*)alloc((size_t)NN * 128 * 4);
    float* D1    = (float*)alloc((size_t)NN * 128 * 4);
    float* D2    = (float*)alloc((size_t)NN * 128 * 4);
    __hip_bfloat16* XbX   = (__hip_bfloat16*)alloc((size_t)NN * FXX * 2);
    __hip_bfloat16* XbDat = (__hip_bfloat16*)alloc((size_t)NN * FWW * 2);
    __hip_bfloat16* Xb1   = (__hip_bfloat16*)alloc((size_t)NN * 128 * 2);
    __hip_bfloat16* XbD1  = (__hip_bfloat16*)alloc((size_t)NN * 128 * 2);
    __hip_bfloat16* XbTmp = (__hip_bfloat16*)alloc((size_t)NN * 128 * 2);
    float* Wsc   = (float*)alloc((size_t)4 * 2048 * 4);
    __hip_bfloat16* Wct0 = (__hip_bfloat16*)alloc((size_t)128 * 1280 * 2);
    __hip_bfloat16* Wct1 = (__hip_bfloat16*)alloc((size_t)128 * 640 * 2);
    __hip_bfloat16* Wct2 = (__hip_bfloat16*)alloc((size_t)128 * 640 * 2);
    __hip_bfloat16* Wct3 = (__hip_bfloat16*)alloc((size_t)128 * 640 * 2);
    float* Ssrc  = (float*)alloc((size_t)NN * 4 * 4);
    float* Sdst  = (float*)alloc((size_t)NN * 4 * 4);
    int* RowPtr  = (int*)alloc((size_t)(NN + 1) * 4);
    int* Cnt     = (int*)alloc((size_t)NN * 4);
    int* Off     = (int*)alloc((size_t)NN * 4);
    int* CsrDst  = (int*)alloc((size_t)EE * 4);
    float* Sums  = (float*)alloc(16);
    float* Att   = (float*)alloc(16);

    // setup: casts, score vectors, combined weights, CSR
    {
        int na = NN * FXX, nb = NN * FWW;
        cast2_kernel<<<(na + nb + 1023) / 1024, 256, 0, stream>>>(x, XbX, na, dat, XbDat, nb);
        WscParams WP;
        WP.t[0] = { W1,  a1s,  a1d,  FXX };
        WP.t[1] = { W2,  a2s,  a2d,  FWW };
        WP.t[2] = { Wd1, ad1s, ad1d, FWW };
        WP.t[3] = { Wd2, ad2s, ad2d, FWW };
        wsc_kernel<<<dim3(256, 1, 4), 256, 0, stream>>>(WP, Wsc);
        WcParams CP;
        CP.t[0] = { W1,  R1,  Wct0, FXX, 1280, 128 * 1280 };
        CP.t[1] = { W2,  R2,  Wct1, FWW, 640,  128 * 640 };
        CP.t[2] = { Wd1, Rd1, Wct2, FWW, 640,  128 * 640 };
        CP.t[3] = { Wd2, Rd2, Wct3, FWW, 640,  128 * 640 };
        wcomb_kernel<<<dim3(640, 1, 4), 256, 0, stream>>>(CP);
    }
    hipMemsetAsync(Cnt, 0, (size_t)NN * 4, stream);
    hipMemsetAsync(Off, 0, (size_t)NN * 4, stream);
    hipMemsetAsync(Sums, 0, 16, stream);
    hist_kernel<<<(EE + 255) / 256, 256, 0, stream>>>(esrc, Cnt);
    scan_kernel<<<1, 1024, 0, stream>>>(Cnt, RowPtr);
    scatter_kernel<<<(EE + 255) / 256, 256, 0, stream>>>(esrc, edst, RowPtr, Off, CsrDst);

    auto layer = [&](const __hip_bfloat16* Xb, int CF, int Lidx, int ch,
                     const __hip_bfloat16* WctL, float* xout, __hip_bfloat16* xbout) {
        const float* wscL = Wsc + (size_t)Lidx * 2048;
        if (CF == 4) {
            score_kernel<4><<<(NN + 3) / 4, 256, 0, stream>>>(Xb, wscL, Ssrc, Sdst);
            agg_cat_kernel<4><<<(NN + 3) / 4, 256, 0, stream>>>(Xb, Ssrc, Sdst, RowPtr, CsrDst, Cat);
            gemm_elu<1280><<<NN / 32, 256, 0, stream>>>(Cat, WctL, xout, xbout, Sums, ch);
        } else {
            score_kernel<2><<<(NN + 3) / 4, 256, 0, stream>>>(Xb, wscL, Ssrc, Sdst);
            agg_cat_kernel<2><<<(NN + 3) / 4, 256, 0, stream>>>(Xb, Ssrc, Sdst, RowPtr, CsrDst, Cat);
            gemm_elu<640><<<NN / 32, 256, 0, stream>>>(Cat, WctL, xout, xbout, Sums, ch);
        }
    };

    layer(XbX,   4, 0, 0, Wct0, X1, Xb1);
    layer(Xb1,   2, 1, 1, Wct1, X2, XbTmp);
    layer(XbDat, 2, 2, 2, Wct2, D1, XbD1);
    layer(XbD1,  2, 3, 3, Wct3, D2, XbTmp);

    att_kernel<<<1, 64, 0, stream>>>(Sums, fc1w, fc1b, fc2w, fc2b, Att);
    final_kernel<<<(NN * 128 + 255) / 256, 256, 0, stream>>>(X1, X2, D1, D2, Att, convw, convb, out);
}

// Round 13
// 339.548 us; speedup vs baseline: 1.1386x; 1.0744x over previous
//
#include <hip/hip_runtime.h>
#include <hip/hip_bf16.h>
#include <math.h>

#define NN 20000
#define EE 320000
#define FXX 256
#define FWW 128
#define NH 4

typedef __attribute__((ext_vector_type(8))) short short8v;
typedef __attribute__((ext_vector_type(4))) float f32x4;

static __device__ __forceinline__ float bf2f(unsigned short s) {
    unsigned int u = ((unsigned int)s) << 16;
    return __builtin_bit_cast(float, u);
}

// round-to-nearest-even fp32 -> bf16 bits
static __device__ __forceinline__ unsigned short f2bf_u16(float f) {
    unsigned int u = __builtin_bit_cast(unsigned int, f);
    unsigned int r = 0x7fffu + ((u >> 16) & 1u);
    return (unsigned short)((u + r) >> 16);
}

// ---------------------------------------------------------------- w~ = W_h @ a (score projection vectors), fp32
struct WscItem { const float* W; const float* as_; const float* ad_; int Fin; };
struct WscParams { WscItem t[4]; };

__global__ __launch_bounds__(256) void wsc_kernel(WscParams p, float* __restrict__ wsc)
{
    int L = blockIdx.z;
    WscItem it = p.t[L];
    int wid = threadIdx.x >> 6, lane = threadIdx.x & 63;
    int r = blockIdx.x * 4 + wid;
    if (r >= it.Fin * 4) return;
    int h = r / it.Fin, k = r - h * it.Fin;
    float2 w2 = *(const float2*)(it.W + ((size_t)(h * it.Fin + k)) * 128 + 2 * lane);
    float2 s2 = *(const float2*)(it.as_ + h * 128 + 2 * lane);
    float2 d2 = *(const float2*)(it.ad_ + h * 128 + 2 * lane);
    float vs = w2.x * s2.x + w2.y * s2.y;
    float vd = w2.x * d2.x + w2.y * d2.y;
    #pragma unroll
    for (int o = 32; o; o >>= 1) { vs += __shfl_xor(vs, o); vd += __shfl_xor(vd, o); }
    if (lane == 0) {
        wsc[(size_t)L * 2048 + h * 256 + k] = vs;
        wsc[(size_t)L * 2048 + (4 + h) * 256 + k] = vd;
    }
}

// ---------------------------------------------------------------- combined GEMM weights: [0.25*W_0;..;0.25*W_3;R] transposed -> [128][KK] bf16
struct WcItem { const float* W; const float* R; __hip_bfloat16* dst; int Fin; int KK; int total; };
struct WcParams { WcItem t[4]; };

__global__ __launch_bounds__(256) void wcomb_kernel(WcParams p)
{
    WcItem it = p.t[blockIdx.z];
    int idx = blockIdx.x * 256 + threadIdx.x;
    if (idx >= it.total) return;     // total = 128*KK
    int c = idx / it.KK;
    int k5 = idx - c * it.KK;
    int f4 = it.Fin * 4;
    float v;
    if (k5 < f4) {
        int h = k5 / it.Fin, k = k5 - h * it.Fin;
        v = 0.25f * it.W[((size_t)(h * it.Fin + k)) * 128 + c];
    } else {
        v = it.R[(size_t)(k5 - f4) * 128 + c];
    }
    it.dst[(size_t)c * it.KK + k5] = __float2bfloat16(v);
}

// ---------------------------------------------------------------- fused cast (fp32->bf16) + scores, wave per node
template<int CF>
__global__ __launch_bounds__(256) void cast_score(const float* __restrict__ Xf,
                                                  __hip_bfloat16* __restrict__ Xb,
                                                  const float* __restrict__ wsc,   // [8][256]
                                                  float* __restrict__ ssrc,
                                                  float* __restrict__ sdst)
{
    const int Fin = CF * 64;
    int wid = threadIdx.x >> 6, lane = threadIdx.x & 63;
    int n = blockIdx.x * 4 + wid;
    if (n >= NN) return;
    int c0 = lane * CF;
    float xv[CF];
    #pragma unroll
    for (int i = 0; i < CF; ++i) xv[i] = Xf[(size_t)n * Fin + c0 + i];
    // cast + store bf16
    union { unsigned u[CF / 2]; unsigned short s[CF]; } pk;
    #pragma unroll
    for (int i = 0; i < CF; ++i) pk.s[i] = f2bf_u16(xv[i]);
    #pragma unroll
    for (int w = 0; w < CF / 2; ++w)
        *(unsigned*)(Xb + (size_t)n * Fin + c0 + w * 2) = pk.u[w];
    // scores
    float acc[8];
    #pragma unroll
    for (int j = 0; j < 8; ++j) {
        const float* w = wsc + j * 256 + c0;
        float s = 0.f;
        #pragma unroll
        for (int i = 0; i < CF; ++i) s += xv[i] * w[i];
        acc[j] = s;
    }
    #pragma unroll
    for (int o = 32; o; o >>= 1)
        #pragma unroll
        for (int j = 0; j < 8; ++j) acc[j] += __shfl_xor(acc[j], o);
    if (lane == 0) {
        *(float4*)(ssrc + (size_t)n * 4) = make_float4(acc[0], acc[1], acc[2], acc[3]);
        *(float4*)(sdst + (size_t)n * 4) = make_float4(acc[4], acc[5], acc[6], acc[7]);
    }
}

// ---------------------------------------------------------------- CSR build
__global__ __launch_bounds__(256) void hist_kernel(const int* __restrict__ src, int* __restrict__ cnt)
{
    int i = blockIdx.x * blockDim.x + threadIdx.x;
    if (i < EE) atomicAdd(&cnt[src[i]], 1);
}

__global__ __launch_bounds__(1024) void scan_kernel(const int* __restrict__ cnt, int* __restrict__ row_ptr)
{
    __shared__ int lds[1024];
    int t = threadIdx.x;
    const int CH = 20;
    int start = t * CH, end = start + CH; if (end > NN) end = NN;
    int sum = 0;
    if (start < NN) for (int i = start; i < end; ++i) sum += cnt[i];
    lds[t] = sum;
    __syncthreads();
    for (int o = 1; o < 1024; o <<= 1) {
        int v = (t >= o) ? lds[t - o] : 0;
        __syncthreads();
        lds[t] += v;
        __syncthreads();
    }
    int run = lds[t] - sum;
    if (start < NN) for (int i = start; i < end; ++i) { row_ptr[i] = run; run += cnt[i]; }
    if (t == 1023) row_ptr[NN] = lds[1023];
}

__global__ __launch_bounds__(256) void scatter_kernel(const int* __restrict__ src,
                                                      const int* __restrict__ dst,
                                                      const int* __restrict__ row_ptr,
                                                      int* __restrict__ off,
                                                      int* __restrict__ csr_dst)
{
    int i = blockIdx.x * blockDim.x + threadIdx.x;
    if (i >= EE) return;
    int s = src[i];
    int p = row_ptr[s] + atomicAdd(&off[s], 1);
    csr_dst[p] = dst[i];
}

// ---------------------------------------------------------------- FUSED softmax + aggregate -> Cat = [G0|G1|G2|G3]  (no X tail)
// wave per node; chunk 0 scalar regs; 4-wide pipelined broadcast-gather.
template<int CF>
__global__ __launch_bounds__(256) void agg_cat_kernel(const __hip_bfloat16* __restrict__ Xb,   // [N][Fin]
                                                      const float* __restrict__ ssrc,
                                                      const float* __restrict__ sdst,
                                                      const int* __restrict__ row_ptr,
                                                      const int* __restrict__ csr_dst,
                                                      __hip_bfloat16* __restrict__ Cat)       // [N][4*Fin]
{
    const int Fin = CF * 64, F4 = 4 * Fin;
    int wid = threadIdx.x >> 6, lane = threadIdx.x & 63;
    int n = blockIdx.x * 4 + wid;
    if (n >= NN) return;
    int r0 = row_ptr[n], r1 = row_ptr[n + 1];
    int deg = r1 - r0;

    float acc[4][CF] = {};

    if (deg > 0) {
        float4 sn = *(const float4*)(ssrc + (size_t)n * 4);
        auto comp_e = [&](int s, int& dout) -> float4 {
            int d = csr_dst[r0 + s];
            dout = d;
            float4 sd = *(const float4*)(sdst + (size_t)d * 4);
            float4 e; float v;
            v = sn.x + sd.x; e.x = v >= 0.f ? v : 0.2f * v;
            v = sn.y + sd.y; e.y = v >= 0.f ? v : 0.2f * v;
            v = sn.z + sd.z; e.z = v >= 0.f ? v : 0.2f * v;
            v = sn.w + sd.w; e.w = v >= 0.f ? v : 0.2f * v;
            return e;
        };

        // ---- softmax over out-edges (chunk 0 scalar regs, cold recompute beyond 64)
        float4 e0 = make_float4(-1e30f, -1e30f, -1e30f, -1e30f);
        int d0 = 0;
        if (lane < deg) e0 = comp_e(lane, d0);
        float4 m = e0;
        for (int s = lane + 64; s < deg; s += 64) {
            int dt; float4 ev = comp_e(s, dt);
            m.x = fmaxf(m.x, ev.x); m.y = fmaxf(m.y, ev.y);
            m.z = fmaxf(m.z, ev.z); m.w = fmaxf(m.w, ev.w);
        }
        #pragma unroll
        for (int o = 32; o; o >>= 1) {
            m.x = fmaxf(m.x, __shfl_xor(m.x, o));
            m.y = fmaxf(m.y, __shfl_xor(m.y, o));
            m.z = fmaxf(m.z, __shfl_xor(m.z, o));
            m.w = fmaxf(m.w, __shfl_xor(m.w, o));
        }
        float4 p0 = make_float4(0.f, 0.f, 0.f, 0.f);
        if (lane < deg) {
            p0.x = expf(e0.x - m.x); p0.y = expf(e0.y - m.y);
            p0.z = expf(e0.z - m.z); p0.w = expf(e0.w - m.w);
        }
        float4 den = p0;
        for (int s = lane + 64; s < deg; s += 64) {
            int dt; float4 ev = comp_e(s, dt);
            den.x += expf(ev.x - m.x); den.y += expf(ev.y - m.y);
            den.z += expf(ev.z - m.z); den.w += expf(ev.w - m.w);
        }
        #pragma unroll
        for (int o = 32; o; o >>= 1) {
            den.x += __shfl_xor(den.x, o); den.y += __shfl_xor(den.y, o);
            den.z += __shfl_xor(den.z, o); den.w += __shfl_xor(den.w, o);
        }
        den.x = 1.f / (den.x + 1e-16f); den.y = 1.f / (den.y + 1e-16f);
        den.z = 1.f / (den.z + 1e-16f); den.w = 1.f / (den.w + 1e-16f);

        float4 a0;
        a0.x = p0.x * den.x; a0.y = p0.y * den.y;
        a0.z = p0.z * den.z; a0.w = p0.w * den.w;

        // ---- hot aggregate: 4-wide pipelined broadcast-gather (chunk 0)
        int cnt0 = min(deg, 64);
        int last = cnt0 - 1;
        for (int base = 0; base < cnt0; base += 4) {
            int j1 = min(base + 1, last), j2 = min(base + 2, last), j3 = min(base + 3, last);
            int dv0 = __shfl(d0, base), dv1 = __shfl(d0, j1);
            int dv2 = __shfl(d0, j2),   dv3 = __shfl(d0, j3);
            union U { unsigned u[CF / 2]; unsigned short s[CF]; };
            U l0, l1, l2, l3;
            #pragma unroll
            for (int w = 0; w < CF / 2; ++w)
                l0.u[w] = *(const unsigned*)(Xb + (size_t)dv0 * Fin + lane * CF + w * 2);
            #pragma unroll
            for (int w = 0; w < CF / 2; ++w)
                l1.u[w] = *(const unsigned*)(Xb + (size_t)dv1 * Fin + lane * CF + w * 2);
            #pragma unroll
            for (int w = 0; w < CF / 2; ++w)
                l2.u[w] = *(const unsigned*)(Xb + (size_t)dv2 * Fin + lane * CF + w * 2);
            #pragma unroll
            for (int w = 0; w < CF / 2; ++w)
                l3.u[w] = *(const unsigned*)(Xb + (size_t)dv3 * Fin + lane * CF + w * 2);

            {
                float ax = __shfl(a0.x, base), ay = __shfl(a0.y, base);
                float az = __shfl(a0.z, base), aw = __shfl(a0.w, base);
                #pragma unroll
                for (int i = 0; i < CF; ++i) {
                    float xv = bf2f(l0.s[i]);
                    acc[0][i] += ax * xv; acc[1][i] += ay * xv;
                    acc[2][i] += az * xv; acc[3][i] += aw * xv;
                }
            }
            if (base + 1 < cnt0) {
                float ax = __shfl(a0.x, j1), ay = __shfl(a0.y, j1);
                float az = __shfl(a0.z, j1), aw = __shfl(a0.w, j1);
                #pragma unroll
                for (int i = 0; i < CF; ++i) {
                    float xv = bf2f(l1.s[i]);
                    acc[0][i] += ax * xv; acc[1][i] += ay * xv;
                    acc[2][i] += az * xv; acc[3][i] += aw * xv;
                }
            }
            if (base + 2 < cnt0) {
                float ax = __shfl(a0.x, j2), ay = __shfl(a0.y, j2);
                float az = __shfl(a0.z, j2), aw = __shfl(a0.w, j2);
                #pragma unroll
                for (int i = 0; i < CF; ++i) {
                    float xv = bf2f(l2.s[i]);
                    acc[0][i] += ax * xv; acc[1][i] += ay * xv;
                    acc[2][i] += az * xv; acc[3][i] += aw * xv;
                }
            }
            if (base + 3 < cnt0) {
                float ax = __shfl(a0.x, j3), ay = __shfl(a0.y, j3);
                float az = __shfl(a0.z, j3), aw = __shfl(a0.w, j3);
                #pragma unroll
                for (int i = 0; i < CF; ++i) {
                    float xv = bf2f(l3.s[i]);
                    acc[0][i] += ax * xv; acc[1][i] += ay * xv;
                    acc[2][i] += az * xv; acc[3][i] += aw * xv;
                }
            }
        }

        // ---- cold chunks (deg > 64): recompute alpha then broadcast
        for (int r = r0 + 64; r < r1; r += 64) {
            int cnt = min(64, r1 - r);
            int d = 0;
            float4 a4 = make_float4(0.f, 0.f, 0.f, 0.f);
            if (r + lane < r1) {
                int dt;
                float4 ev = comp_e(r - r0 + lane, dt);
                d = dt;
                a4.x = expf(ev.x - m.x) * den.x; a4.y = expf(ev.y - m.y) * den.y;
                a4.z = expf(ev.z - m.z) * den.z; a4.w = expf(ev.w - m.w) * den.w;
            }
            for (int j = 0; j < cnt; ++j) {
                int ddv = __shfl(d, j);
                float ax = __shfl(a4.x, j), ay = __shfl(a4.y, j);
                float az = __shfl(a4.z, j), aw = __shfl(a4.w, j);
                union { unsigned u[CF / 2]; unsigned short s[CF]; } ld;
                #pragma unroll
                for (int w = 0; w < CF / 2; ++w)
                    ld.u[w] = *(const unsigned*)(Xb + (size_t)ddv * Fin + lane * CF + w * 2);
                #pragma unroll
                for (int i = 0; i < CF; ++i) {
                    float xv = bf2f(ld.s[i]);
                    acc[0][i] += ax * xv; acc[1][i] += ay * xv;
                    acc[2][i] += az * xv; acc[3][i] += aw * xv;
                }
            }
        }
    }

    __hip_bfloat16* crow = Cat + (size_t)n * F4;
    #pragma unroll
    for (int h = 0; h < 4; ++h) {
        union { unsigned u[CF / 2]; unsigned short s[CF]; } pk;
        #pragma unroll
        for (int i = 0; i < CF; ++i) pk.s[i] = f2bf_u16(acc[h][i]);
        #pragma unroll
        for (int w = 0; w < CF / 2; ++w)
            *(unsigned*)(crow + h * Fin + lane * CF + w * 2) = pk.u[w];
    }
}

// ---------------------------------------------------------------- MFMA GEMM + ELU + fused SE-pool + (optional) next-layer scores
// A[k] = Cat[n][k] for k<F4, Xb[n][k-F4] for k>=F4. block = 32 rows x 128 cols.
template<int F4, int FIN, bool DOSC>
__global__ __launch_bounds__(256) void gemm_elu(const __hip_bfloat16* __restrict__ Cat,   // [N][F4]
                                                const __hip_bfloat16* __restrict__ Xb,    // [N][FIN]
                                                const __hip_bfloat16* __restrict__ Wct,   // [128][F4+FIN]
                                                float* __restrict__ xout,
                                                __hip_bfloat16* __restrict__ xbout,
                                                float* __restrict__ sums, int ch,
                                                const float* __restrict__ wscN,           // [8][256] next-layer
                                                float* __restrict__ ssrcN,
                                                float* __restrict__ sdstN)
{
    const int KK = F4 + FIN;
    const int BK = 64;
    const int NIT = KK / BK;
    __shared__ short As[2][32 * 72];
    __shared__ short Bs[2][128 * 72];
    __shared__ float ls[4];
    __shared__ float sred[4][4][4][8];   // [wid][grp][r][j]

    int tid = threadIdx.x, lane = tid & 63, wid = tid >> 6;
    int wr = wid >> 1, wc = wid & 1;
    int ar = lane & 15, kg = lane >> 4;
    int row0 = blockIdx.x * 32;         // 20000 = 32*625

    int a_row = tid >> 3, a_seg = tid & 7;
    int b_col = tid >> 1, b_seg0 = (tid & 1) * 4;

    const __hip_bfloat16* AgC = Cat + (size_t)(row0 + a_row) * F4 + a_seg * 8;
    const __hip_bfloat16* AgX = Xb + (size_t)(row0 + a_row) * FIN + a_seg * 8;
    const __hip_bfloat16* Bg = Wct + (size_t)b_col * KK + b_seg0 * 8;

    short8v fa, fb0, fb1, fb2, fb3;
    f32x4 acc[4] = {};

    fa  = *(const short8v*)(AgC);
    fb0 = *(const short8v*)(Bg);
    fb1 = *(const short8v*)(Bg + 8);
    fb2 = *(const short8v*)(Bg + 16);
    fb3 = *(const short8v*)(Bg + 24);
    *(short8v*)(&As[0][a_row * 72 + a_seg * 8]) = fa;
    *(short8v*)(&Bs[0][b_col * 72 + (b_seg0 + 0) * 8]) = fb0;
    *(short8v*)(&Bs[0][b_col * 72 + (b_seg0 + 1) * 8]) = fb1;
    *(short8v*)(&Bs[0][b_col * 72 + (b_seg0 + 2) * 8]) = fb2;
    *(short8v*)(&Bs[0][b_col * 72 + (b_seg0 + 3) * 8]) = fb3;

    int cur = 0;
    for (int it = 0; it < NIT; ++it) {
        if (it + 1 < NIT) {
            int kb = (it + 1) * BK;
            fa  = (kb < F4) ? *(const short8v*)(AgC + kb) : *(const short8v*)(AgX + (kb - F4));
            fb0 = *(const short8v*)(Bg + kb);
            fb1 = *(const short8v*)(Bg + kb + 8);
            fb2 = *(const short8v*)(Bg + kb + 16);
            fb3 = *(const short8v*)(Bg + kb + 24);
        }
        __syncthreads();
        #pragma unroll
        for (int ks = 0; ks < 2; ++ks) {
            short8v a = *(const short8v*)(&As[cur][(wr * 16 + ar) * 72 + ks * 32 + kg * 8]);
            #pragma unroll
            for (int nb = 0; nb < 4; ++nb) {
                short8v b = *(const short8v*)(&Bs[cur][(wc * 64 + nb * 16 + ar) * 72 + ks * 32 + kg * 8]);
                acc[nb] = __builtin_amdgcn_mfma_f32_16x16x32_bf16(a, b, acc[nb], 0, 0, 0);
            }
        }
        if (it + 1 < NIT) {
            int nb2 = cur ^ 1;
            *(short8v*)(&As[nb2][a_row * 72 + a_seg * 8]) = fa;
            *(short8v*)(&Bs[nb2][b_col * 72 + (b_seg0 + 0) * 8]) = fb0;
            *(short8v*)(&Bs[nb2][b_col * 72 + (b_seg0 + 1) * 8]) = fb1;
            *(short8v*)(&Bs[nb2][b_col * 72 + (b_seg0 + 2) * 8]) = fb2;
            *(short8v*)(&Bs[nb2][b_col * 72 + (b_seg0 + 3) * 8]) = fb3;
        }
        cur ^= 1;
    }

    float lsum = 0.f;
    float vpost[4][4];
    int rsub = (lane >> 4) * 4;
    #pragma unroll
    for (int nb = 0; nb < 4; ++nb) {
        int col = wc * 64 + nb * 16 + ar;
        #pragma unroll
        for (int r = 0; r < 4; ++r) {
            int row = row0 + wr * 16 + rsub + r;
            float v = acc[nb][r];
            v = v > 0.f ? v : expm1f(v);
            vpost[nb][r] = v;
            lsum += v;
            xout[(size_t)row * 128 + col] = v;
            xbout[(size_t)row * 128 + col] = __float2bfloat16(v);
        }
    }
    // fused SE pooling partial
    #pragma unroll
    for (int o = 32; o; o >>= 1) lsum += __shfl_xor(lsum, o);
    if (lane == 0) ls[wid] = lsum;

    if (DOSC) {
        // next-layer scores: sc[r][j] = sum over this thread's cols, then 16-lane + cross-wave reduce
        float sc[4][8] = {};
        #pragma unroll
        for (int j = 0; j < 8; ++j) {
            #pragma unroll
            for (int nb = 0; nb < 4; ++nb) {
                float wv = wscN[j * 256 + wc * 64 + nb * 16 + ar];
                #pragma unroll
                for (int r = 0; r < 4; ++r) sc[r][j] += vpost[nb][r] * wv;
            }
        }
        #pragma unroll
        for (int o = 8; o; o >>= 1)
            #pragma unroll
            for (int r = 0; r < 4; ++r)
                #pragma unroll
                for (int j = 0; j < 8; ++j) sc[r][j] += __shfl_xor(sc[r][j], o);
        if (ar == 0) {
            int grp = lane >> 4;
            #pragma unroll
            for (int r = 0; r < 4; ++r)
                #pragma unroll
                for (int j = 0; j < 8; ++j) sred[wid][grp][r][j] = sc[r][j];
        }
    }
    __syncthreads();
    if (tid == 0) atomicAdd(&sums[ch], ls[0] + ls[1] + ls[2] + ls[3]);
    if (DOSC) {
        // 256 threads = 32 rows x 8 j
        int row_local = tid >> 3, j = tid & 7;
        int w_r = row_local >> 4, grp = (row_local >> 2) & 3, r = row_local & 3;
        float total = sred[w_r * 2 + 0][grp][r][j] + sred[w_r * 2 + 1][grp][r][j];
        int row = row0 + row_local;
        if (j < 4) ssrcN[(size_t)row * 4 + j] = total;
        else       sdstN[(size_t)row * 4 + (j - 4)] = total;
    }
}

// ---------------------------------------------------------------- SE MLP -> att[4]
__global__ void att_kernel(const float* __restrict__ sums,
                           const float* __restrict__ fc1w, const float* __restrict__ fc1b,
                           const float* __restrict__ fc2w, const float* __restrict__ fc2b,
                           float* __restrict__ att)
{
    if (threadIdx.x != 0 || blockIdx.x != 0) return;
    float avg[4];
    for (int c = 0; c < 4; ++c) avg[c] = sums[c] * (1.f / (NN * 128.f));
    float z[20];
    for (int j = 0; j < 20; ++j) {
        float v = fc1b[j];
        for (int c = 0; c < 4; ++c) v += avg[c] * fc1w[c * 20 + j];
        z[j] = v;
    }
    for (int c = 0; c < 4; ++c) {
        float v = fc2b[c];
        for (int j = 0; j < 20; ++j) v += z[j] * fc2w[j * 4 + c];
        att[c] = 1.f / (1.f + expf(-v));
    }
}

__global__ __launch_bounds__(256) void final_kernel(const float* __restrict__ x1,
                                                    const float* __restrict__ x2,
                                                    const float* __restrict__ d1,
                                                    const float* __restrict__ d2,
                                                    const float* __restrict__ att,
                                                    const float* __restrict__ convw,
                                                    const float* __restrict__ convb,
                                                    float* __restrict__ out)
{
    int i = blockIdx.x * blockDim.x + threadIdx.x;
    if (i >= NN * 128) return;
    float a0 = att[0], a1 = att[1], a2 = att[2], a3 = att[3];
    float w0 = convw[0], w1 = convw[1], w2 = convw[2], w3 = convw[3];
    float v = convb[0];
    v += w0 * fmaxf(a0 * x1[i], 0.f);
    v += w1 * fmaxf(a1 * x2[i], 0.f);
    v += w2 * fmaxf(a2 * d1[i], 0.f);
    v += w3 * fmaxf(a3 * d2[i], 0.f);
    out[i] = v;
}

// ---------------------------------------------------------------- host
extern "C" void kernel_launch(void* const* d_in, const int* in_sizes, int n_in,
                              void* d_out, int out_size, void* d_ws, size_t ws_size,
                              hipStream_t stream)
{
    (void)in_sizes; (void)n_in; (void)out_size; (void)ws_size;
    const float* x    = (const float*)d_in[0];
    const float* dat  = (const float*)d_in[1];
    const float* W1   = (const float*)d_in[2];
    const float* a1s  = (const float*)d_in[3];
    const float* a1d  = (const float*)d_in[4];
    const float* R1   = (const float*)d_in[5];
    const float* W2   = (const float*)d_in[6];
    const float* a2s  = (const float*)d_in[7];
    const float* a2d  = (const float*)d_in[8];
    const float* R2   = (const float*)d_in[9];
    const float* Wd1  = (const float*)d_in[10];
    const float* ad1s = (const float*)d_in[11];
    const float* ad1d = (const float*)d_in[12];
    const float* Rd1  = (const float*)d_in[13];
    const float* Wd2  = (const float*)d_in[14];
    const float* ad2s = (const float*)d_in[15];
    const float* ad2d = (const float*)d_in[16];
    const float* Rd2  = (const float*)d_in[17];
    const float* fc1w = (const float*)d_in[18];
    const float* fc1b = (const float*)d_in[19];
    const float* fc2w = (const float*)d_in[20];
    const float* fc2b = (const float*)d_in[21];
    const float* convw= (const float*)d_in[22];
    const float* convb= (const float*)d_in[23];
    const int*   eidx = (const int*)d_in[24];
    const int* esrc = eidx;
    const int* edst = eidx + EE;
    float* out = (float*)d_out;

    char* base = (char*)d_ws;
    size_t woff = 0;
    auto alloc = [&](size_t bytes) -> void* {
        void* p = base + woff;
        woff = (woff + bytes + 255) & ~(size_t)255;
        return p;
    };
    __hip_bfloat16* Cat  = (__hip_bfloat16*)alloc((size_t)NN * 1024 * 2);
    float* X1    = (float*)alloc((size_t)NN * 128 * 4);
    float* X2    = (float*)alloc((size_t)NN * 128 * 4);
    float* D1    = (float*)alloc((size_t)NN * 128 * 4);
    float* D2    = (float*)alloc((size_t)NN * 128 * 4);
    __hip_bfloat16* XbX   = (__hip_bfloat16*)alloc((size_t)NN * FXX * 2);
    __hip_bfloat16* XbDat = (__hip_bfloat16*)alloc((size_t)NN * FWW * 2);
    __hip_bfloat16* Xb1   = (__hip_bfloat16*)alloc((size_t)NN * 128 * 2);
    __hip_bfloat16* XbD1  = (__hip_bfloat16*)alloc((size_t)NN * 128 * 2);
    __hip_bfloat16* XbTmp = (__hip_bfloat16*)alloc((size_t)NN * 128 * 2);
    float* Wsc   = (float*)alloc((size_t)4 * 2048 * 4);
    __hip_bfloat16* Wct0 = (__hip_bfloat16*)alloc((size_t)128 * 1280 * 2);
    __hip_bfloat16* Wct1 = (__hip_bfloat16*)alloc((size_t)128 * 640 * 2);
    __hip_bfloat16* Wct2 = (__hip_bfloat16*)alloc((size_t)128 * 640 * 2);
    __hip_bfloat16* Wct3 = (__hip_bfloat16*)alloc((size_t)128 * 640 * 2);
    float* SsrcX = (float*)alloc((size_t)NN * 4 * 4);
    float* SdstX = (float*)alloc((size_t)NN * 4 * 4);
    float* Ssrc1 = (float*)alloc((size_t)NN * 4 * 4);
    float* Sdst1 = (float*)alloc((size_t)NN * 4 * 4);
    float* SsrcD = (float*)alloc((size_t)NN * 4 * 4);
    float* SdstD = (float*)alloc((size_t)NN * 4 * 4);
    float* Ssrc3 = (float*)alloc((size_t)NN * 4 * 4);
    float* Sdst3 = (float*)alloc((size_t)NN * 4 * 4);
    int* RowPtr  = (int*)alloc((size_t)(NN + 1) * 4);
    int* Cnt     = (int*)alloc((size_t)NN * 4);
    int* Off     = (int*)alloc((size_t)NN * 4);
    int* CsrDst  = (int*)alloc((size_t)EE * 4);
    float* Sums  = (float*)alloc(16);
    float* Att   = (float*)alloc(16);

    // setup: score vectors first (cast_score needs them), combined weights, casts+scores, CSR
    {
        WscParams WP;
        WP.t[0] = { W1,  a1s,  a1d,  FXX };
        WP.t[1] = { W2,  a2s,  a2d,  FWW };
        WP.t[2] = { Wd1, ad1s, ad1d, FWW };
        WP.t[3] = { Wd2, ad2s, ad2d, FWW };
        wsc_kernel<<<dim3(256, 1, 4), 256, 0, stream>>>(WP, Wsc);
        WcParams CP;
        CP.t[0] = { W1,  R1,  Wct0, FXX, 1280, 128 * 1280 };
        CP.t[1] = { W2,  R2,  Wct1, FWW, 640,  128 * 640 };
        CP.t[2] = { Wd1, Rd1, Wct2, FWW, 640,  128 * 640 };
        CP.t[3] = { Wd2, Rd2, Wct3, FWW, 640,  128 * 640 };
        wcomb_kernel<<<dim3(640, 1, 4), 256, 0, stream>>>(CP);
        cast_score<4><<<(NN + 3) / 4, 256, 0, stream>>>(x, XbX, Wsc, SsrcX, SdstX);
        cast_score<2><<<(NN + 3) / 4, 256, 0, stream>>>(dat, XbDat, Wsc + 2 * 2048, SsrcD, SdstD);
    }
    hipMemsetAsync(Cnt, 0, (size_t)NN * 4, stream);
    hipMemsetAsync(Off, 0, (size_t)NN * 4, stream);
    hipMemsetAsync(Sums, 0, 16, stream);
    hist_kernel<<<(EE + 255) / 256, 256, 0, stream>>>(esrc, Cnt);
    scan_kernel<<<1, 1024, 0, stream>>>(Cnt, RowPtr);
    scatter_kernel<<<(EE + 255) / 256, 256, 0, stream>>>(esrc, edst, RowPtr, Off, CsrDst);

    // layer 0: x -> X1 (+ scores for layer 1)
    agg_cat_kernel<4><<<(NN + 3) / 4, 256, 0, stream>>>(XbX, SsrcX, SdstX, RowPtr, CsrDst, Cat);
    gemm_elu<1024, 256, true><<<NN / 32, 256, 0, stream>>>(Cat, XbX, Wct0, X1, Xb1, Sums, 0,
                                                           Wsc + 1 * 2048, Ssrc1, Sdst1);
    // layer 1: X1 -> X2
    agg_cat_kernel<2><<<(NN + 3) / 4, 256, 0, stream>>>(Xb1, Ssrc1, Sdst1, RowPtr, CsrDst, Cat);
    gemm_elu<512, 128, false><<<NN / 32, 256, 0, stream>>>(Cat, Xb1, Wct1, X2, XbTmp, Sums, 1,
                                                           nullptr, nullptr, nullptr);
    // layer 2: dat -> D1 (+ scores for layer 3)
    agg_cat_kernel<2><<<(NN + 3) / 4, 256, 0, stream>>>(XbDat, SsrcD, SdstD, RowPtr, CsrDst, Cat);
    gemm_elu<512, 128, true><<<NN / 32, 256, 0, stream>>>(Cat, XbDat, Wct2, D1, XbD1, Sums, 2,
                                                          Wsc + 3 * 2048, Ssrc3, Sdst3);
    // layer 3: D1 -> D2
    agg_cat_kernel<2><<<(NN + 3) / 4, 256, 0, stream>>>(XbD1, Ssrc3, Sdst3, RowPtr, CsrDst, Cat);
    gemm_elu<512, 128, false><<<NN / 32, 256, 0, stream>>>(Cat, XbD1, Wct3, D2, XbTmp, Sums, 3,
                                                           nullptr, nullptr, nullptr);

    att_kernel<<<1, 64, 0, stream>>>(Sums, fc1w, fc1b, fc2w, fc2b, Att);
    final_kernel<<<(NN * 128 + 255) / 256, 256, 0, stream>>>(X1, X2, D1, D2, Att, convw, convb, out);
}

// Round 14
// 307.355 us; speedup vs baseline: 1.2579x; 1.1047x over previous
//
#include <hip/hip_runtime.h>
#include <hip/hip_bf16.h>
#include <math.h>

#define NN 20000
#define EE 320000
#define FXX 256
#define FWW 128
#define NH 4

typedef __attribute__((ext_vector_type(8))) short short8v;
typedef __attribute__((ext_vector_type(4))) float f32x4;

static __device__ __forceinline__ float bf2f(unsigned short s) {
    unsigned int u = ((unsigned int)s) << 16;
    return __builtin_bit_cast(float, u);
}

static __device__ __forceinline__ unsigned short f2bf_u16(float f) {
    unsigned int u = __builtin_bit_cast(unsigned int, f);
    unsigned int r = 0x7fffu + ((u >> 16) & 1u);
    return (unsigned short)((u + r) >> 16);
}

// ---------------------------------------------------------------- w~ = W_h @ a (score projection vectors), fp32
struct WscItem { const float* W; const float* as_; const float* ad_; int Fin; };
struct WscParams { WscItem t[4]; };

__global__ __launch_bounds__(256) void wsc_kernel(WscParams p, float* __restrict__ wsc)
{
    int L = blockIdx.z;
    WscItem it = p.t[L];
    int wid = threadIdx.x >> 6, lane = threadIdx.x & 63;
    int r = blockIdx.x * 4 + wid;
    if (r >= it.Fin * 4) return;
    int h = r / it.Fin, k = r - h * it.Fin;
    float2 w2 = *(const float2*)(it.W + ((size_t)(h * it.Fin + k)) * 128 + 2 * lane);
    float2 s2 = *(const float2*)(it.as_ + h * 128 + 2 * lane);
    float2 d2 = *(const float2*)(it.ad_ + h * 128 + 2 * lane);
    float vs = w2.x * s2.x + w2.y * s2.y;
    float vd = w2.x * d2.x + w2.y * d2.y;
    #pragma unroll
    for (int o = 32; o; o >>= 1) { vs += __shfl_xor(vs, o); vd += __shfl_xor(vd, o); }
    if (lane == 0) {
        wsc[(size_t)L * 2048 + h * 256 + k] = vs;
        wsc[(size_t)L * 2048 + (4 + h) * 256 + k] = vd;
    }
}

// ---------------------------------------------------------------- combined GEMM weights
struct WcItem { const float* W; const float* R; __hip_bfloat16* dst; int Fin; int KK; int total; };
struct WcParams { WcItem t[4]; };

__global__ __launch_bounds__(256) void wcomb_kernel(WcParams p)
{
    WcItem it = p.t[blockIdx.z];
    int idx = blockIdx.x * 256 + threadIdx.x;
    if (idx >= it.total) return;
    int c = idx / it.KK;
    int k5 = idx - c * it.KK;
    int f4 = it.Fin * 4;
    float v;
    if (k5 < f4) {
        int h = k5 / it.Fin, k = k5 - h * it.Fin;
        v = 0.25f * it.W[((size_t)(h * it.Fin + k)) * 128 + c];
    } else {
        v = it.R[(size_t)(k5 - f4) * 128 + c];
    }
    it.dst[(size_t)c * it.KK + k5] = __float2bfloat16(v);
}

// ---------------------------------------------------------------- fused cast + scores (both inputs, one dispatch)
template<int CF>
static __device__ __forceinline__ void cast_score_body(const float* __restrict__ Xf,
                                                       __hip_bfloat16* __restrict__ Xb,
                                                       const float* __restrict__ wsc,
                                                       float* __restrict__ ssrc,
                                                       float* __restrict__ sdst)
{
    const int Fin = CF * 64;
    int wid = threadIdx.x >> 6, lane = threadIdx.x & 63;
    int n = blockIdx.x * 4 + wid;
    if (n >= NN) return;
    int c0 = lane * CF;
    float xv[CF];
    #pragma unroll
    for (int i = 0; i < CF; ++i) xv[i] = Xf[(size_t)n * Fin + c0 + i];
    union { unsigned u[CF / 2]; unsigned short s[CF]; } pk;
    #pragma unroll
    for (int i = 0; i < CF; ++i) pk.s[i] = f2bf_u16(xv[i]);
    #pragma unroll
    for (int w = 0; w < CF / 2; ++w)
        *(unsigned*)(Xb + (size_t)n * Fin + c0 + w * 2) = pk.u[w];
    float acc[8];
    #pragma unroll
    for (int j = 0; j < 8; ++j) {
        const float* w = wsc + j * 256 + c0;
        float s = 0.f;
        #pragma unroll
        for (int i = 0; i < CF; ++i) s += xv[i] * w[i];
        acc[j] = s;
    }
    #pragma unroll
    for (int o = 32; o; o >>= 1)
        #pragma unroll
        for (int j = 0; j < 8; ++j) acc[j] += __shfl_xor(acc[j], o);
    if (lane == 0) {
        *(float4*)(ssrc + (size_t)n * 4) = make_float4(acc[0], acc[1], acc[2], acc[3]);
        *(float4*)(sdst + (size_t)n * 4) = make_float4(acc[4], acc[5], acc[6], acc[7]);
    }
}

struct CSPair {
    const float* Xf[2]; __hip_bfloat16* Xb[2];
    const float* wsc[2]; float* ssrc[2]; float* sdst[2];
};

__global__ __launch_bounds__(256) void cast_score_pair(CSPair p)
{
    if (blockIdx.y == 0)
        cast_score_body<4>(p.Xf[0], p.Xb[0], p.wsc[0], p.ssrc[0], p.sdst[0]);
    else
        cast_score_body<2>(p.Xf[1], p.Xb[1], p.wsc[1], p.ssrc[1], p.sdst[1]);
}

// ---------------------------------------------------------------- CSR build
__global__ __launch_bounds__(256) void hist_kernel(const int* __restrict__ src, int* __restrict__ cnt)
{
    int i = blockIdx.x * blockDim.x + threadIdx.x;
    if (i < EE) atomicAdd(&cnt[src[i]], 1);
}

__global__ __launch_bounds__(1024) void scan_kernel(const int* __restrict__ cnt, int* __restrict__ row_ptr)
{
    __shared__ int lds[1024];
    int t = threadIdx.x;
    const int CH = 20;
    int start = t * CH, end = start + CH; if (end > NN) end = NN;
    int sum = 0;
    if (start < NN) for (int i = start; i < end; ++i) sum += cnt[i];
    lds[t] = sum;
    __syncthreads();
    for (int o = 1; o < 1024; o <<= 1) {
        int v = (t >= o) ? lds[t - o] : 0;
        __syncthreads();
        lds[t] += v;
        __syncthreads();
    }
    int run = lds[t] - sum;
    if (start < NN) for (int i = start; i < end; ++i) { row_ptr[i] = run; run += cnt[i]; }
    if (t == 1023) row_ptr[NN] = lds[1023];
}

__global__ __launch_bounds__(256) void scatter_kernel(const int* __restrict__ src,
                                                      const int* __restrict__ dst,
                                                      const int* __restrict__ row_ptr,
                                                      int* __restrict__ off,
                                                      int* __restrict__ csr_dst)
{
    int i = blockIdx.x * blockDim.x + threadIdx.x;
    if (i >= EE) return;
    int s = src[i];
    int p = row_ptr[s] + atomicAdd(&off[s], 1);
    csr_dst[p] = dst[i];
}

// ---------------------------------------------------------------- FUSED softmax + aggregate body (unchanged math from R13)
template<int CF>
static __device__ __forceinline__ void agg_body(const __hip_bfloat16* __restrict__ Xb,
                                                const float* __restrict__ ssrc,
                                                const float* __restrict__ sdst,
                                                const int* __restrict__ row_ptr,
                                                const int* __restrict__ csr_dst,
                                                __hip_bfloat16* __restrict__ Cat)
{
    const int Fin = CF * 64, F4 = 4 * Fin;
    int wid = threadIdx.x >> 6, lane = threadIdx.x & 63;
    int n = blockIdx.x * 4 + wid;
    if (n >= NN) return;
    int r0 = row_ptr[n], r1 = row_ptr[n + 1];
    int deg = r1 - r0;

    float acc[4][CF] = {};

    if (deg > 0) {
        float4 sn = *(const float4*)(ssrc + (size_t)n * 4);
        auto comp_e = [&](int s, int& dout) -> float4 {
            int d = csr_dst[r0 + s];
            dout = d;
            float4 sd = *(const float4*)(sdst + (size_t)d * 4);
            float4 e; float v;
            v = sn.x + sd.x; e.x = v >= 0.f ? v : 0.2f * v;
            v = sn.y + sd.y; e.y = v >= 0.f ? v : 0.2f * v;
            v = sn.z + sd.z; e.z = v >= 0.f ? v : 0.2f * v;
            v = sn.w + sd.w; e.w = v >= 0.f ? v : 0.2f * v;
            return e;
        };

        float4 e0 = make_float4(-1e30f, -1e30f, -1e30f, -1e30f);
        int d0 = 0;
        if (lane < deg) e0 = comp_e(lane, d0);
        float4 m = e0;
        for (int s = lane + 64; s < deg; s += 64) {
            int dt; float4 ev = comp_e(s, dt);
            m.x = fmaxf(m.x, ev.x); m.y = fmaxf(m.y, ev.y);
            m.z = fmaxf(m.z, ev.z); m.w = fmaxf(m.w, ev.w);
        }
        #pragma unroll
        for (int o = 32; o; o >>= 1) {
            m.x = fmaxf(m.x, __shfl_xor(m.x, o));
            m.y = fmaxf(m.y, __shfl_xor(m.y, o));
            m.z = fmaxf(m.z, __shfl_xor(m.z, o));
            m.w = fmaxf(m.w, __shfl_xor(m.w, o));
        }
        float4 p0 = make_float4(0.f, 0.f, 0.f, 0.f);
        if (lane < deg) {
            p0.x = expf(e0.x - m.x); p0.y = expf(e0.y - m.y);
            p0.z = expf(e0.z - m.z); p0.w = expf(e0.w - m.w);
        }
        float4 den = p0;
        for (int s = lane + 64; s < deg; s += 64) {
            int dt; float4 ev = comp_e(s, dt);
            den.x += expf(ev.x - m.x); den.y += expf(ev.y - m.y);
            den.z += expf(ev.z - m.z); den.w += expf(ev.w - m.w);
        }
        #pragma unroll
        for (int o = 32; o; o >>= 1) {
            den.x += __shfl_xor(den.x, o); den.y += __shfl_xor(den.y, o);
            den.z += __shfl_xor(den.z, o); den.w += __shfl_xor(den.w, o);
        }
        den.x = 1.f / (den.x + 1e-16f); den.y = 1.f / (den.y + 1e-16f);
        den.z = 1.f / (den.z + 1e-16f); den.w = 1.f / (den.w + 1e-16f);

        float4 a0;
        a0.x = p0.x * den.x; a0.y = p0.y * den.y;
        a0.z = p0.z * den.z; a0.w = p0.w * den.w;

        int cnt0 = min(deg, 64);
        int last = cnt0 - 1;
        for (int base = 0; base < cnt0; base += 4) {
            int j1 = min(base + 1, last), j2 = min(base + 2, last), j3 = min(base + 3, last);
            int dv0 = __shfl(d0, base), dv1 = __shfl(d0, j1);
            int dv2 = __shfl(d0, j2),   dv3 = __shfl(d0, j3);
            union U { unsigned u[CF / 2]; unsigned short s[CF]; };
            U l0, l1, l2, l3;
            #pragma unroll
            for (int w = 0; w < CF / 2; ++w)
                l0.u[w] = *(const unsigned*)(Xb + (size_t)dv0 * Fin + lane * CF + w * 2);
            #pragma unroll
            for (int w = 0; w < CF / 2; ++w)
                l1.u[w] = *(const unsigned*)(Xb + (size_t)dv1 * Fin + lane * CF + w * 2);
            #pragma unroll
            for (int w = 0; w < CF / 2; ++w)
                l2.u[w] = *(const unsigned*)(Xb + (size_t)dv2 * Fin + lane * CF + w * 2);
            #pragma unroll
            for (int w = 0; w < CF / 2; ++w)
                l3.u[w] = *(const unsigned*)(Xb + (size_t)dv3 * Fin + lane * CF + w * 2);

            {
                float ax = __shfl(a0.x, base), ay = __shfl(a0.y, base);
                float az = __shfl(a0.z, base), aw = __shfl(a0.w, base);
                #pragma unroll
                for (int i = 0; i < CF; ++i) {
                    float xv = bf2f(l0.s[i]);
                    acc[0][i] += ax * xv; acc[1][i] += ay * xv;
                    acc[2][i] += az * xv; acc[3][i] += aw * xv;
                }
            }
            if (base + 1 < cnt0) {
                float ax = __shfl(a0.x, j1), ay = __shfl(a0.y, j1);
                float az = __shfl(a0.z, j1), aw = __shfl(a0.w, j1);
                #pragma unroll
                for (int i = 0; i < CF; ++i) {
                    float xv = bf2f(l1.s[i]);
                    acc[0][i] += ax * xv; acc[1][i] += ay * xv;
                    acc[2][i] += az * xv; acc[3][i] += aw * xv;
                }
            }
            if (base + 2 < cnt0) {
                float ax = __shfl(a0.x, j2), ay = __shfl(a0.y, j2);
                float az = __shfl(a0.z, j2), aw = __shfl(a0.w, j2);
                #pragma unroll
                for (int i = 0; i < CF; ++i) {
                    float xv = bf2f(l2.s[i]);
                    acc[0][i] += ax * xv; acc[1][i] += ay * xv;
                    acc[2][i] += az * xv; acc[3][i] += aw * xv;
                }
            }
            if (base + 3 < cnt0) {
                float ax = __shfl(a0.x, j3), ay = __shfl(a0.y, j3);
                float az = __shfl(a0.z, j3), aw = __shfl(a0.w, j3);
                #pragma unroll
                for (int i = 0; i < CF; ++i) {
                    float xv = bf2f(l3.s[i]);
                    acc[0][i] += ax * xv; acc[1][i] += ay * xv;
                    acc[2][i] += az * xv; acc[3][i] += aw * xv;
                }
            }
        }

        for (int r = r0 + 64; r < r1; r += 64) {
            int cnt = min(64, r1 - r);
            int d = 0;
            float4 a4 = make_float4(0.f, 0.f, 0.f, 0.f);
            if (r + lane < r1) {
                int dt;
                float4 ev = comp_e(r - r0 + lane, dt);
                d = dt;
                a4.x = expf(ev.x - m.x) * den.x; a4.y = expf(ev.y - m.y) * den.y;
                a4.z = expf(ev.z - m.z) * den.z; a4.w = expf(ev.w - m.w) * den.w;
            }
            for (int j = 0; j < cnt; ++j) {
                int ddv = __shfl(d, j);
                float ax = __shfl(a4.x, j), ay = __shfl(a4.y, j);
                float az = __shfl(a4.z, j), aw = __shfl(a4.w, j);
                union { unsigned u[CF / 2]; unsigned short s[CF]; } ld;
                #pragma unroll
                for (int w = 0; w < CF / 2; ++w)
                    ld.u[w] = *(const unsigned*)(Xb + (size_t)ddv * Fin + lane * CF + w * 2);
                #pragma unroll
                for (int i = 0; i < CF; ++i) {
                    float xv = bf2f(ld.s[i]);
                    acc[0][i] += ax * xv; acc[1][i] += ay * xv;
                    acc[2][i] += az * xv; acc[3][i] += aw * xv;
                }
            }
        }
    }

    __hip_bfloat16* crow = Cat + (size_t)n * F4;
    #pragma unroll
    for (int h = 0; h < 4; ++h) {
        union { unsigned u[CF / 2]; unsigned short s[CF]; } pk;
        #pragma unroll
        for (int i = 0; i < CF; ++i) pk.s[i] = f2bf_u16(acc[h][i]);
        #pragma unroll
        for (int w = 0; w < CF / 2; ++w)
            *(unsigned*)(crow + h * Fin + lane * CF + w * 2) = pk.u[w];
    }
}

struct AggPair {
    const __hip_bfloat16* Xb[2];
    const float* ssrc[2]; const float* sdst[2];
    __hip_bfloat16* Cat[2];
};

template<int CF0, int CF1>
__global__ __launch_bounds__(256) void agg_pair_kernel(AggPair p,
                                                       const int* __restrict__ row_ptr,
                                                       const int* __restrict__ csr_dst)
{
    if (blockIdx.y == 0)
        agg_body<CF0>(p.Xb[0], p.ssrc[0], p.sdst[0], row_ptr, csr_dst, p.Cat[0]);
    else
        agg_body<CF1>(p.Xb[1], p.ssrc[1], p.sdst[1], row_ptr, csr_dst, p.Cat[1]);
}

// ---------------------------------------------------------------- MFMA GEMM + ELU + SE-pool + optional next scores (runtime dims)
struct GemmArgs {
    const __hip_bfloat16 *Cat, *Xb, *Wct;
    float* xout; __hip_bfloat16* xbout;
    const float* wscN; float *ssrcN, *sdstN;
    int F4, FIN, ch;
};
struct GemmPair { GemmArgs g[2]; };

__global__ __launch_bounds__(256) void gemm_pair_kernel(GemmPair p, float* __restrict__ sums)
{
    GemmArgs a = (blockIdx.y == 0) ? p.g[0] : p.g[1];
    const int F4 = a.F4, FIN = a.FIN;
    const int KK = F4 + FIN;
    const int BK = 64;
    const int NIT = KK / BK;
    __shared__ short As[2][32 * 72];
    __shared__ short Bs[2][128 * 72];
    __shared__ float ls[4];
    __shared__ float sred[4][4][4][8];

    int tid = threadIdx.x, lane = tid & 63, wid = tid >> 6;
    int wr = wid >> 1, wc = wid & 1;
    int ar = lane & 15, kg = lane >> 4;
    int row0 = blockIdx.x * 32;

    int a_row = tid >> 3, a_seg = tid & 7;
    int b_col = tid >> 1, b_seg0 = (tid & 1) * 4;

    const __hip_bfloat16* AgC = a.Cat + (size_t)(row0 + a_row) * F4 + a_seg * 8;
    const __hip_bfloat16* AgX = a.Xb + (size_t)(row0 + a_row) * FIN + a_seg * 8;
    const __hip_bfloat16* Bg = a.Wct + (size_t)b_col * KK + b_seg0 * 8;

    short8v fa, fb0, fb1, fb2, fb3;
    f32x4 acc[4] = {};

    fa  = *(const short8v*)(AgC);
    fb0 = *(const short8v*)(Bg);
    fb1 = *(const short8v*)(Bg + 8);
    fb2 = *(const short8v*)(Bg + 16);
    fb3 = *(const short8v*)(Bg + 24);
    *(short8v*)(&As[0][a_row * 72 + a_seg * 8]) = fa;
    *(short8v*)(&Bs[0][b_col * 72 + (b_seg0 + 0) * 8]) = fb0;
    *(short8v*)(&Bs[0][b_col * 72 + (b_seg0 + 1) * 8]) = fb1;
    *(short8v*)(&Bs[0][b_col * 72 + (b_seg0 + 2) * 8]) = fb2;
    *(short8v*)(&Bs[0][b_col * 72 + (b_seg0 + 3) * 8]) = fb3;

    int cur = 0;
    for (int it = 0; it < NIT; ++it) {
        if (it + 1 < NIT) {
            int kb = (it + 1) * BK;
            fa  = (kb < F4) ? *(const short8v*)(AgC + kb) : *(const short8v*)(AgX + (kb - F4));
            fb0 = *(const short8v*)(Bg + kb);
            fb1 = *(const short8v*)(Bg + kb + 8);
            fb2 = *(const short8v*)(Bg + kb + 16);
            fb3 = *(const short8v*)(Bg + kb + 24);
        }
        __syncthreads();
        #pragma unroll
        for (int ks = 0; ks < 2; ++ks) {
            short8v av = *(const short8v*)(&As[cur][(wr * 16 + ar) * 72 + ks * 32 + kg * 8]);
            #pragma unroll
            for (int nb = 0; nb < 4; ++nb) {
                short8v bv = *(const short8v*)(&Bs[cur][(wc * 64 + nb * 16 + ar) * 72 + ks * 32 + kg * 8]);
                acc[nb] = __builtin_amdgcn_mfma_f32_16x16x32_bf16(av, bv, acc[nb], 0, 0, 0);
            }
        }
        if (it + 1 < NIT) {
            int nb2 = cur ^ 1;
            *(short8v*)(&As[nb2][a_row * 72 + a_seg * 8]) = fa;
            *(short8v*)(&Bs[nb2][b_col * 72 + (b_seg0 + 0) * 8]) = fb0;
            *(short8v*)(&Bs[nb2][b_col * 72 + (b_seg0 + 1) * 8]) = fb1;
            *(short8v*)(&Bs[nb2][b_col * 72 + (b_seg0 + 2) * 8]) = fb2;
            *(short8v*)(&Bs[nb2][b_col * 72 + (b_seg0 + 3) * 8]) = fb3;
        }
        cur ^= 1;
    }

    float lsum = 0.f;
    float vpost[4][4];
    int rsub = (lane >> 4) * 4;
    #pragma unroll
    for (int nb = 0; nb < 4; ++nb) {
        int col = wc * 64 + nb * 16 + ar;
        #pragma unroll
        for (int r = 0; r < 4; ++r) {
            int row = row0 + wr * 16 + rsub + r;
            float v = acc[nb][r];
            v = v > 0.f ? v : expm1f(v);
            vpost[nb][r] = v;
            lsum += v;
            a.xout[(size_t)row * 128 + col] = v;
            a.xbout[(size_t)row * 128 + col] = __float2bfloat16(v);
        }
    }
    #pragma unroll
    for (int o = 32; o; o >>= 1) lsum += __shfl_xor(lsum, o);
    if (lane == 0) ls[wid] = lsum;

    bool dosc = a.wscN != nullptr;
    if (dosc) {
        float sc[4][8] = {};
        #pragma unroll
        for (int j = 0; j < 8; ++j) {
            #pragma unroll
            for (int nb = 0; nb < 4; ++nb) {
                float wv = a.wscN[j * 256 + wc * 64 + nb * 16 + ar];
                #pragma unroll
                for (int r = 0; r < 4; ++r) sc[r][j] += vpost[nb][r] * wv;
            }
        }
        #pragma unroll
        for (int o = 8; o; o >>= 1)
            #pragma unroll
            for (int r = 0; r < 4; ++r)
                #pragma unroll
                for (int j = 0; j < 8; ++j) sc[r][j] += __shfl_xor(sc[r][j], o);
        if (ar == 0) {
            int grp = lane >> 4;
            #pragma unroll
            for (int r = 0; r < 4; ++r)
                #pragma unroll
                for (int j = 0; j < 8; ++j) sred[wid][grp][r][j] = sc[r][j];
        }
    }
    __syncthreads();
    if (tid == 0) atomicAdd(&sums[a.ch], ls[0] + ls[1] + ls[2] + ls[3]);
    if (dosc) {
        int row_local = tid >> 3, j = tid & 7;
        int w_r = row_local >> 4, grp = (row_local >> 2) & 3, r = row_local & 3;
        float total = sred[w_r * 2 + 0][grp][r][j] + sred[w_r * 2 + 1][grp][r][j];
        int row = row0 + row_local;
        if (j < 4) a.ssrcN[(size_t)row * 4 + j] = total;
        else       a.sdstN[(size_t)row * 4 + (j - 4)] = total;
    }
}

// ---------------------------------------------------------------- SE MLP -> att[4]
__global__ void att_kernel(const float* __restrict__ sums,
                           const float* __restrict__ fc1w, const float* __restrict__ fc1b,
                           const float* __restrict__ fc2w, const float* __restrict__ fc2b,
                           float* __restrict__ att)
{
    if (threadIdx.x != 0 || blockIdx.x != 0) return;
    float avg[4];
    for (int c = 0; c < 4; ++c) avg[c] = sums[c] * (1.f / (NN * 128.f));
    float z[20];
    for (int j = 0; j < 20; ++j) {
        float v = fc1b[j];
        for (int c = 0; c < 4; ++c) v += avg[c] * fc1w[c * 20 + j];
        z[j] = v;
    }
    for (int c = 0; c < 4; ++c) {
        float v = fc2b[c];
        for (int j = 0; j < 20; ++j) v += z[j] * fc2w[j * 4 + c];
        att[c] = 1.f / (1.f + expf(-v));
    }
}

__global__ __launch_bounds__(256) void final_kernel(const float* __restrict__ x1,
                                                    const float* __restrict__ x2,
                                                    const float* __restrict__ d1,
                                                    const float* __restrict__ d2,
                                                    const float* __restrict__ att,
                                                    const float* __restrict__ convw,
                                                    const float* __restrict__ convb,
                                                    float* __restrict__ out)
{
    int i = blockIdx.x * blockDim.x + threadIdx.x;
    if (i >= NN * 128) return;
    float a0 = att[0], a1 = att[1], a2 = att[2], a3 = att[3];
    float w0 = convw[0], w1 = convw[1], w2 = convw[2], w3 = convw[3];
    float v = convb[0];
    v += w0 * fmaxf(a0 * x1[i], 0.f);
    v += w1 * fmaxf(a1 * x2[i], 0.f);
    v += w2 * fmaxf(a2 * d1[i], 0.f);
    v += w3 * fmaxf(a3 * d2[i], 0.f);
    out[i] = v;
}

// ---------------------------------------------------------------- host
extern "C" void kernel_launch(void* const* d_in, const int* in_sizes, int n_in,
                              void* d_out, int out_size, void* d_ws, size_t ws_size,
                              hipStream_t stream)
{
    (void)in_sizes; (void)n_in; (void)out_size; (void)ws_size;
    const float* x    = (const float*)d_in[0];
    const float* dat  = (const float*)d_in[1];
    const float* W1   = (const float*)d_in[2];
    const float* a1s  = (const float*)d_in[3];
    const float* a1d  = (const float*)d_in[4];
    const float* R1   = (const float*)d_in[5];
    const float* W2   = (const float*)d_in[6];
    const float* a2s  = (const float*)d_in[7];
    const float* a2d  = (const float*)d_in[8];
    const float* R2   = (const float*)d_in[9];
    const float* Wd1  = (const float*)d_in[10];
    const float* ad1s = (const float*)d_in[11];
    const float* ad1d = (const float*)d_in[12];
    const float* Rd1  = (const float*)d_in[13];
    const float* Wd2  = (const float*)d_in[14];
    const float* ad2s = (const float*)d_in[15];
    const float* ad2d = (const float*)d_in[16];
    const float* Rd2  = (const float*)d_in[17];
    const float* fc1w = (const float*)d_in[18];
    const float* fc1b = (const float*)d_in[19];
    const float* fc2w = (const float*)d_in[20];
    const float* fc2b = (const float*)d_in[21];
    const float* convw= (const float*)d_in[22];
    const float* convb= (const float*)d_in[23];
    const int*   eidx = (const int*)d_in[24];
    const int* esrc = eidx;
    const int* edst = eidx + EE;
    float* out = (float*)d_out;

    char* base = (char*)d_ws;
    size_t woff = 0;
    auto alloc = [&](size_t bytes) -> void* {
        void* p = base + woff;
        woff = (woff + bytes + 255) & ~(size_t)255;
        return p;
    };
    __hip_bfloat16* Cat0 = (__hip_bfloat16*)alloc((size_t)NN * 1024 * 2);
    __hip_bfloat16* Cat2 = (__hip_bfloat16*)alloc((size_t)NN * 512 * 2);
    float* X1    = (float*)alloc((size_t)NN * 128 * 4);
    float* X2    = (float*)alloc((size_t)NN * 128 * 4);
    float* D1    = (float*)alloc((size_t)NN * 128 * 4);
    float* D2    = (float*)alloc((size_t)NN * 128 * 4);
    __hip_bfloat16* XbX   = (__hip_bfloat16*)alloc((size_t)NN * FXX * 2);
    __hip_bfloat16* XbDat = (__hip_bfloat16*)alloc((size_t)NN * FWW * 2);
    __hip_bfloat16* Xb1   = (__hip_bfloat16*)alloc((size_t)NN * 128 * 2);
    __hip_bfloat16* XbD1  = (__hip_bfloat16*)alloc((size_t)NN * 128 * 2);
    __hip_bfloat16* XbTmp = (__hip_bfloat16*)alloc((size_t)NN * 128 * 2);
    __hip_bfloat16* XbTm2 = (__hip_bfloat16*)alloc((size_t)NN * 128 * 2);
    float* Wsc   = (float*)alloc((size_t)4 * 2048 * 4);
    __hip_bfloat16* Wct0 = (__hip_bfloat16*)alloc((size_t)128 * 1280 * 2);
    __hip_bfloat16* Wct1 = (__hip_bfloat16*)alloc((size_t)128 * 640 * 2);
    __hip_bfloat16* Wct2 = (__hip_bfloat16*)alloc((size_t)128 * 640 * 2);
    __hip_bfloat16* Wct3 = (__hip_bfloat16*)alloc((size_t)128 * 640 * 2);
    float* SsrcX = (float*)alloc((size_t)NN * 4 * 4);
    float* SdstX = (float*)alloc((size_t)NN * 4 * 4);
    float* Ssrc1 = (float*)alloc((size_t)NN * 4 * 4);
    float* Sdst1 = (float*)alloc((size_t)NN * 4 * 4);
    float* SsrcD = (float*)alloc((size_t)NN * 4 * 4);
    float* SdstD = (float*)alloc((size_t)NN * 4 * 4);
    float* Ssrc3 = (float*)alloc((size_t)NN * 4 * 4);
    float* Sdst3 = (float*)alloc((size_t)NN * 4 * 4);
    int* RowPtr  = (int*)alloc((size_t)(NN + 1) * 4);
    int* Cnt     = (int*)alloc((size_t)NN * 4);
    int* Off     = (int*)alloc((size_t)NN * 4);
    int* CsrDst  = (int*)alloc((size_t)EE * 4);
    float* Sums  = (float*)alloc(16);
    float* Att   = (float*)alloc(16);

    // setup
    {
        WscParams WP;
        WP.t[0] = { W1,  a1s,  a1d,  FXX };
        WP.t[1] = { W2,  a2s,  a2d,  FWW };
        WP.t[2] = { Wd1, ad1s, ad1d, FWW };
        WP.t[3] = { Wd2, ad2s, ad2d, FWW };
        wsc_kernel<<<dim3(256, 1, 4), 256, 0, stream>>>(WP, Wsc);
        WcParams CP;
        CP.t[0] = { W1,  R1,  Wct0, FXX, 1280, 128 * 1280 };
        CP.t[1] = { W2,  R2,  Wct1, FWW, 640,  128 * 640 };
        CP.t[2] = { Wd1, Rd1, Wct2, FWW, 640,  128 * 640 };
        CP.t[3] = { Wd2, Rd2, Wct3, FWW, 640,  128 * 640 };
        wcomb_kernel<<<dim3(640, 1, 4), 256, 0, stream>>>(CP);
        CSPair CS;
        CS.Xf[0] = x;   CS.Xb[0] = XbX;   CS.wsc[0] = Wsc;            CS.ssrc[0] = SsrcX; CS.sdst[0] = SdstX;
        CS.Xf[1] = dat; CS.Xb[1] = XbDat; CS.wsc[1] = Wsc + 2 * 2048; CS.ssrc[1] = SsrcD; CS.sdst[1] = SdstD;
        cast_score_pair<<<dim3((NN + 3) / 4, 2), 256, 0, stream>>>(CS);
    }
    hipMemsetAsync(Cnt, 0, (size_t)NN * 4, stream);
    hipMemsetAsync(Off, 0, (size_t)NN * 4, stream);
    hipMemsetAsync(Sums, 0, 16, stream);
    hist_kernel<<<(EE + 255) / 256, 256, 0, stream>>>(esrc, Cnt);
    scan_kernel<<<1, 1024, 0, stream>>>(Cnt, RowPtr);
    scatter_kernel<<<(EE + 255) / 256, 256, 0, stream>>>(esrc, edst, RowPtr, Off, CsrDst);

    // stage A: agg layers {0, 2}
    {
        AggPair AP;
        AP.Xb[0] = XbX;   AP.ssrc[0] = SsrcX; AP.sdst[0] = SdstX; AP.Cat[0] = Cat0;
        AP.Xb[1] = XbDat; AP.ssrc[1] = SsrcD; AP.sdst[1] = SdstD; AP.Cat[1] = Cat2;
        agg_pair_kernel<4, 2><<<dim3((NN + 3) / 4, 2), 256, 0, stream>>>(AP, RowPtr, CsrDst);
    }
    // stage B: gemm layers {0, 2} (+ next-layer scores)
    {
        GemmPair GP;
        GP.g[0] = { Cat0, XbX,   Wct0, X1, Xb1,  Wsc + 1 * 2048, Ssrc1, Sdst1, 1024, 256, 0 };
        GP.g[1] = { Cat2, XbDat, Wct2, D1, XbD1, Wsc + 3 * 2048, Ssrc3, Sdst3, 512,  128, 2 };
        gemm_pair_kernel<<<dim3(NN / 32, 2), 256, 0, stream>>>(GP, Sums);
    }
    // stage C: agg layers {1, 3}
    {
        AggPair AP;
        AP.Xb[0] = Xb1;  AP.ssrc[0] = Ssrc1; AP.sdst[0] = Sdst1; AP.Cat[0] = Cat0;
        AP.Xb[1] = XbD1; AP.ssrc[1] = Ssrc3; AP.sdst[1] = Sdst3; AP.Cat[1] = Cat2;
        agg_pair_kernel<2, 2><<<dim3((NN + 3) / 4, 2), 256, 0, stream>>>(AP, RowPtr, CsrDst);
    }
    // stage D: gemm layers {1, 3}
    {
        GemmPair GP;
        GP.g[0] = { Cat0, Xb1,  Wct1, X2, XbTmp, nullptr, nullptr, nullptr, 512, 128, 1 };
        GP.g[1] = { Cat2, XbD1, Wct3, D2, XbTm2, nullptr, nullptr, nullptr, 512, 128, 3 };
        gemm_pair_kernel<<<dim3(NN / 32, 2), 256, 0, stream>>>(GP, Sums);
    }

    att_kernel<<<1, 64, 0, stream>>>(Sums, fc1w, fc1b, fc2w, fc2b, Att);
    final_kernel<<<(NN * 128 + 255) / 256, 256, 0, stream>>>(X1, X2, D1, D2, Att, convw, convb, out);
}